// Round 1
// baseline (4564.027 us; speedup 1.0000x reference)
//
#include <hip/hip_runtime.h>

#define N_NODES 20000
#define N_EDGES 160000
#define N_GRAPHS 64
#define IN_DIM 128
#define HID 512
#define N_CLASSES 16

// ---------------- degree kernels ----------------
__global__ void deg_kernel(const int* __restrict__ src, const int* __restrict__ dst,
                           float* __restrict__ dout, float* __restrict__ din, int E) {
  int e = blockIdx.x * blockDim.x + threadIdx.x;
  if (e < E) {
    atomicAdd(dout + src[e], 1.0f);
    atomicAdd(din + dst[e], 1.0f);
  }
}

__global__ void isqrt_kernel(float* __restrict__ d, int n) {
  int i = blockIdx.x * blockDim.x + threadIdx.x;
  if (i < n) d[i] = rsqrtf(fmaxf(d[i], 1.0f));
}

// ---------------- scaled SGEMM: C[M,N] = (scale[m] * A[m,:]) @ W[K,N] ----------------
// 64x64 block tile, BK=16, 256 threads, 4x4 micro-tile per thread.
#define BM 64
#define BN 64
#define BK 16
__global__ __launch_bounds__(256) void gemm_scaled(
    const float* __restrict__ A, const float* __restrict__ W,
    const float* __restrict__ scale, float* __restrict__ C,
    int M, int K, int N) {
  __shared__ float As[BM][BK + 1];
  __shared__ float Bs[BK][BN + 1];

  const int t = threadIdx.x;
  const int ty = t >> 4;        // 0..15
  const int tx = t & 15;        // 0..15
  const int row0 = blockIdx.x * BM;
  const int col0 = blockIdx.y * BN;

  // A-load mapping: 64 rows x 16 cols, float4 per thread
  const int aRow = t >> 2;          // 0..63
  const int aCol = (t & 3) * 4;     // 0,4,8,12
  // B-load mapping: 16 rows x 64 cols, float4 per thread
  const int bRow = t >> 4;          // 0..15
  const int bCol = (t & 15) * 4;    // 0..60

  const int arow_g = row0 + aRow;
  const float sc = (arow_g < M) ? scale[arow_g] : 0.0f;

  float acc[4][4] = {};

  for (int k0 = 0; k0 < K; k0 += BK) {
    if (arow_g < M) {
      const float4 v = *(const float4*)(A + (size_t)arow_g * K + k0 + aCol);
      As[aRow][aCol + 0] = v.x * sc;
      As[aRow][aCol + 1] = v.y * sc;
      As[aRow][aCol + 2] = v.z * sc;
      As[aRow][aCol + 3] = v.w * sc;
    } else {
      As[aRow][aCol + 0] = 0.f; As[aRow][aCol + 1] = 0.f;
      As[aRow][aCol + 2] = 0.f; As[aRow][aCol + 3] = 0.f;
    }
    {
      const float4 w = *(const float4*)(W + (size_t)(k0 + bRow) * N + col0 + bCol);
      Bs[bRow][bCol + 0] = w.x;
      Bs[bRow][bCol + 1] = w.y;
      Bs[bRow][bCol + 2] = w.z;
      Bs[bRow][bCol + 3] = w.w;
    }
    __syncthreads();

#pragma unroll
    for (int kk = 0; kk < BK; kk++) {
      float a0 = As[ty * 4 + 0][kk];
      float a1 = As[ty * 4 + 1][kk];
      float a2 = As[ty * 4 + 2][kk];
      float a3 = As[ty * 4 + 3][kk];
      float b0 = Bs[kk][tx * 4 + 0];
      float b1 = Bs[kk][tx * 4 + 1];
      float b2 = Bs[kk][tx * 4 + 2];
      float b3 = Bs[kk][tx * 4 + 3];
      acc[0][0] += a0 * b0; acc[0][1] += a0 * b1; acc[0][2] += a0 * b2; acc[0][3] += a0 * b3;
      acc[1][0] += a1 * b0; acc[1][1] += a1 * b1; acc[1][2] += a1 * b2; acc[1][3] += a1 * b3;
      acc[2][0] += a2 * b0; acc[2][1] += a2 * b1; acc[2][2] += a2 * b2; acc[2][3] += a2 * b3;
      acc[3][0] += a3 * b0; acc[3][1] += a3 * b1; acc[3][2] += a3 * b2; acc[3][3] += a3 * b3;
    }
    __syncthreads();
  }

#pragma unroll
  for (int i = 0; i < 4; i++) {
    const int r = row0 + ty * 4 + i;
    if (r < M) {
      float4 v = make_float4(acc[i][0], acc[i][1], acc[i][2], acc[i][3]);
      *(float4*)(C + (size_t)r * N + col0 + tx * 4) = v;
    }
  }
}

// ---------------- edge scatter-add: agg[dst[e],:] += hp[src[e],:] ----------------
// one thread = one (edge, 4-float chunk); HID/4 = 128 chunks per edge
__global__ void scatter_kernel(const float* __restrict__ hp, const int* __restrict__ src,
                               const int* __restrict__ dst, float* __restrict__ agg, int E) {
  const long long tid = (long long)blockIdx.x * blockDim.x + threadIdx.x;
  const int e = (int)(tid >> 7);
  if (e >= E) return;
  const int chunk = ((int)tid & 127) * 4;
  const int s = src[e];
  const int d = dst[e];
  const float4 v = *(const float4*)(hp + (size_t)s * HID + chunk);
  float* p = agg + (size_t)d * HID + chunk;
  atomicAdd(p + 0, v.x);
  atomicAdd(p + 1, v.y);
  atomicAdd(p + 2, v.z);
  atomicAdd(p + 3, v.w);
}

// ---------------- epilogue: h = relu(agg * din_isqrt[row] + b[col]) in place ----------------
__global__ void finalize_kernel(float* __restrict__ h, const float* __restrict__ din,
                                const float* __restrict__ b, int total) {
  int i = blockIdx.x * blockDim.x + threadIdx.x;
  if (i >= total) return;
  const int row = i >> 9;   // /512
  const int col = i & 511;
  float v = h[i] * din[row] + b[col];
  h[i] = fmaxf(v, 0.0f);
}

// ---------------- pooling ----------------
__global__ void pool_feat_kernel(const float* __restrict__ h, const int* __restrict__ gid,
                                 float* __restrict__ hg) {
  const long long tid = (long long)blockIdx.x * blockDim.x + threadIdx.x;
  const int node = (int)(tid >> 7);
  if (node >= N_NODES) return;
  const int col = ((int)tid & 127) * 4;
  const int g = gid[node];
  const float4 v = *(const float4*)(h + (size_t)node * HID + col);
  float* p = hg + (size_t)g * HID + col;
  atomicAdd(p + 0, v.x);
  atomicAdd(p + 1, v.y);
  atomicAdd(p + 2, v.z);
  atomicAdd(p + 3, v.w);
}

__global__ void pool_cnt_kernel(const int* __restrict__ gid, float* __restrict__ cnt) {
  int n = blockIdx.x * blockDim.x + threadIdx.x;
  if (n < N_NODES) atomicAdd(cnt + gid[n], 1.0f);
}

__global__ void mean_kernel(float* __restrict__ hg, const float* __restrict__ cnt) {
  int i = blockIdx.x * blockDim.x + threadIdx.x;
  if (i >= N_GRAPHS * HID) return;
  hg[i] /= fmaxf(cnt[i >> 9], 1.0f);
}

// ---------------- small dense: out[G,N] = act(in[G,K] @ W[K,N] + b[N]) ----------------
__global__ void dense_kernel(const float* __restrict__ in, const float* __restrict__ W,
                             const float* __restrict__ b, float* __restrict__ out,
                             int G, int K, int N, int relu) {
  int idx = blockIdx.x * blockDim.x + threadIdx.x;
  if (idx >= G * N) return;
  int g = idx / N, n = idx % N;
  float acc = b[n];
  for (int k = 0; k < K; k++) acc += in[(size_t)g * K + k] * W[(size_t)k * N + n];
  if (relu) acc = fmaxf(acc, 0.0f);
  out[idx] = acc;
}

extern "C" void kernel_launch(void* const* d_in, const int* in_sizes, int n_in,
                              void* d_out, int out_size, void* d_ws, size_t ws_size,
                              hipStream_t stream) {
  const float* x   = (const float*)d_in[0];
  const int*   src = (const int*)d_in[1];
  const int*   dst = (const int*)d_in[2];
  const int*   gid = (const int*)d_in[3];
  const float* W1  = (const float*)d_in[4];  const float* b1  = (const float*)d_in[5];
  const float* W2  = (const float*)d_in[6];  const float* b2  = (const float*)d_in[7];
  const float* W3  = (const float*)d_in[8];  const float* b3  = (const float*)d_in[9];
  const float* Wc1 = (const float*)d_in[10]; const float* bc1 = (const float*)d_in[11];
  const float* Wc2 = (const float*)d_in[12]; const float* bc2 = (const float*)d_in[13];
  const float* Wc3 = (const float*)d_in[14]; const float* bc3 = (const float*)d_in[15];
  float* out = (float*)d_out;

  float* ws   = (float*)d_ws;
  float* bufA = ws;                                  // [N_NODES, HID]
  float* bufB = bufA + (size_t)N_NODES * HID;        // [N_NODES, HID]
  float* dosq = bufB + (size_t)N_NODES * HID;        // [N_NODES] dout_isqrt
  float* disq = dosq + N_NODES;                      // [N_NODES] din_isqrt
  float* hg   = disq + N_NODES;                      // [N_GRAPHS, HID]
  float* cnt  = hg + N_GRAPHS * HID;                 // [N_GRAPHS]
  float* m1   = cnt + N_GRAPHS;                      // [N_GRAPHS, HID]
  float* m2   = m1 + N_GRAPHS * HID;                 // [N_GRAPHS, HID]

  const size_t HBYTES = (size_t)N_NODES * HID * sizeof(float);

  // degrees -> isqrt (dosq and disq are contiguous: one memset, one transform)
  hipMemsetAsync(dosq, 0, 2 * N_NODES * sizeof(float), stream);
  deg_kernel<<<(N_EDGES + 255) / 256, 256, 0, stream>>>(src, dst, dosq, disq, N_EDGES);
  isqrt_kernel<<<(2 * N_NODES + 255) / 256, 256, 0, stream>>>(dosq, 2 * N_NODES);

  const dim3 ggrid((N_NODES + BM - 1) / BM, HID / BN);
  const int scatter_blocks = (N_EDGES * (HID / 4) + 255) / 256;
  const int fin_blocks = (N_NODES * HID + 255) / 256;

  // ---- conv layer 1: x[20000,128] ----
  gemm_scaled<<<ggrid, 256, 0, stream>>>(x, W1, dosq, bufB, N_NODES, IN_DIM, HID);
  hipMemsetAsync(bufA, 0, HBYTES, stream);
  scatter_kernel<<<scatter_blocks, 256, 0, stream>>>(bufB, src, dst, bufA, N_EDGES);
  finalize_kernel<<<fin_blocks, 256, 0, stream>>>(bufA, disq, b1, N_NODES * HID);

  // ---- conv layer 2 ----
  gemm_scaled<<<ggrid, 256, 0, stream>>>(bufA, W2, dosq, bufB, N_NODES, HID, HID);
  hipMemsetAsync(bufA, 0, HBYTES, stream);
  scatter_kernel<<<scatter_blocks, 256, 0, stream>>>(bufB, src, dst, bufA, N_EDGES);
  finalize_kernel<<<fin_blocks, 256, 0, stream>>>(bufA, disq, b2, N_NODES * HID);

  // ---- conv layer 3 ----
  gemm_scaled<<<ggrid, 256, 0, stream>>>(bufA, W3, dosq, bufB, N_NODES, HID, HID);
  hipMemsetAsync(bufA, 0, HBYTES, stream);
  scatter_kernel<<<scatter_blocks, 256, 0, stream>>>(bufB, src, dst, bufA, N_EDGES);
  finalize_kernel<<<fin_blocks, 256, 0, stream>>>(bufA, disq, b3, N_NODES * HID);

  // ---- mean pooling ----
  hipMemsetAsync(hg, 0, (N_GRAPHS * HID + N_GRAPHS) * sizeof(float), stream);
  pool_feat_kernel<<<(N_NODES * (HID / 4) + 255) / 256, 256, 0, stream>>>(bufA, gid, hg);
  pool_cnt_kernel<<<(N_NODES + 255) / 256, 256, 0, stream>>>(gid, cnt);
  mean_kernel<<<(N_GRAPHS * HID + 255) / 256, 256, 0, stream>>>(hg, cnt);

  // ---- classifier MLP ----
  dense_kernel<<<(N_GRAPHS * HID + 255) / 256, 256, 0, stream>>>(hg, Wc1, bc1, m1, N_GRAPHS, HID, HID, 1);
  dense_kernel<<<(N_GRAPHS * HID + 255) / 256, 256, 0, stream>>>(m1, Wc2, bc2, m2, N_GRAPHS, HID, HID, 1);
  dense_kernel<<<(N_GRAPHS * N_CLASSES + 255) / 256, 256, 0, stream>>>(m2, Wc3, bc3, out, N_GRAPHS, HID, N_CLASSES, 0);
}

// Round 2
// 1164.520 us; speedup vs baseline: 3.9192x; 3.9192x over previous
//
#include <hip/hip_runtime.h>

#define N_NODES 20000
#define N_EDGES 160000
#define N_GRAPHS 64
#define IN_DIM 128
#define HID 512
#define N_CLASSES 16

// ---------------- degrees (int) ----------------
__global__ void deg_kernel(const int* __restrict__ src, const int* __restrict__ dst,
                           int* __restrict__ dout, int* __restrict__ din, int E) {
  int e = blockIdx.x * blockDim.x + threadIdx.x;
  if (e < E) {
    atomicAdd(dout + src[e], 1);
    atomicAdd(din + dst[e], 1);
  }
}

// f[i] = rsqrt(max(deg[i],1)) over 2*N_NODES contiguous (dout_i,din_i)->(dosq,disq)
__global__ void isqrt_from_int(const int* __restrict__ di, float* __restrict__ f, int n) {
  int i = blockIdx.x * blockDim.x + threadIdx.x;
  if (i < n) f[i] = rsqrtf(fmaxf((float)di[i], 1.0f));
}

// ---------------- single-block exclusive scan: row_start[0..n] from deg[0..n-1] ----------------
__global__ __launch_bounds__(1024) void scan_kernel(const int* __restrict__ deg,
                                                    int* __restrict__ row_start, int n) {
  __shared__ int s[1024];
  __shared__ int carry;
  if (threadIdx.x == 0) { carry = 0; row_start[0] = 0; }
  __syncthreads();
  for (int base = 0; base < n; base += 1024) {
    const int i = base + threadIdx.x;
    s[threadIdx.x] = (i < n) ? deg[i] : 0;
    __syncthreads();
#pragma unroll
    for (int off = 1; off < 1024; off <<= 1) {
      int t = (threadIdx.x >= off) ? s[threadIdx.x - off] : 0;
      __syncthreads();
      s[threadIdx.x] += t;
      __syncthreads();
    }
    const int c = carry;
    if (i < n) row_start[i + 1] = c + s[threadIdx.x];
    __syncthreads();
    if (threadIdx.x == 0) carry = c + s[1023];
    __syncthreads();
  }
}

// ---------------- CSR fill: bucket src by dst ----------------
__global__ void csr_fill(const int* __restrict__ src, const int* __restrict__ dst,
                         const int* __restrict__ row_start, int* __restrict__ cursor,
                         int* __restrict__ csr_src, int E) {
  int e = blockIdx.x * blockDim.x + threadIdx.x;
  if (e < E) {
    const int d = dst[e];
    const int pos = atomicAdd(cursor + d, 1);
    csr_src[row_start[d] + pos] = src[e];
  }
}

// ---------------- scaled SGEMM: C[M,N] = (scale[m] * A[m,:]) @ W[K,N] ----------------
#define BM 64
#define BN 64
#define BK 16
__global__ __launch_bounds__(256) void gemm_scaled(
    const float* __restrict__ A, const float* __restrict__ W,
    const float* __restrict__ scale, float* __restrict__ C,
    int M, int K, int N) {
  __shared__ float As[BM][BK + 1];
  __shared__ float Bs[BK][BN + 1];

  const int t = threadIdx.x;
  const int ty = t >> 4;
  const int tx = t & 15;
  const int row0 = blockIdx.x * BM;
  const int col0 = blockIdx.y * BN;

  const int aRow = t >> 2;
  const int aCol = (t & 3) * 4;
  const int bRow = t >> 4;
  const int bCol = (t & 15) * 4;

  const int arow_g = row0 + aRow;
  const float sc = (arow_g < M) ? scale[arow_g] : 0.0f;

  float acc[4][4] = {};

  for (int k0 = 0; k0 < K; k0 += BK) {
    if (arow_g < M) {
      const float4 v = *(const float4*)(A + (size_t)arow_g * K + k0 + aCol);
      As[aRow][aCol + 0] = v.x * sc;
      As[aRow][aCol + 1] = v.y * sc;
      As[aRow][aCol + 2] = v.z * sc;
      As[aRow][aCol + 3] = v.w * sc;
    } else {
      As[aRow][aCol + 0] = 0.f; As[aRow][aCol + 1] = 0.f;
      As[aRow][aCol + 2] = 0.f; As[aRow][aCol + 3] = 0.f;
    }
    {
      const float4 w = *(const float4*)(W + (size_t)(k0 + bRow) * N + col0 + bCol);
      Bs[bRow][bCol + 0] = w.x;
      Bs[bRow][bCol + 1] = w.y;
      Bs[bRow][bCol + 2] = w.z;
      Bs[bRow][bCol + 3] = w.w;
    }
    __syncthreads();

#pragma unroll
    for (int kk = 0; kk < BK; kk++) {
      float a0 = As[ty * 4 + 0][kk];
      float a1 = As[ty * 4 + 1][kk];
      float a2 = As[ty * 4 + 2][kk];
      float a3 = As[ty * 4 + 3][kk];
      float b0 = Bs[kk][tx * 4 + 0];
      float b1 = Bs[kk][tx * 4 + 1];
      float b2 = Bs[kk][tx * 4 + 2];
      float b3 = Bs[kk][tx * 4 + 3];
      acc[0][0] += a0 * b0; acc[0][1] += a0 * b1; acc[0][2] += a0 * b2; acc[0][3] += a0 * b3;
      acc[1][0] += a1 * b0; acc[1][1] += a1 * b1; acc[1][2] += a1 * b2; acc[1][3] += a1 * b3;
      acc[2][0] += a2 * b0; acc[2][1] += a2 * b1; acc[2][2] += a2 * b2; acc[2][3] += a2 * b3;
      acc[3][0] += a3 * b0; acc[3][1] += a3 * b1; acc[3][2] += a3 * b2; acc[3][3] += a3 * b3;
    }
    __syncthreads();
  }

#pragma unroll
  for (int i = 0; i < 4; i++) {
    const int r = row0 + ty * 4 + i;
    if (r < M) {
      float4 v = make_float4(acc[i][0], acc[i][1], acc[i][2], acc[i][3]);
      *(float4*)(C + (size_t)r * N + col0 + tx * 4) = v;
    }
  }
}

// ---------------- CSR gather-aggregate, fused din_isqrt + bias + relu ----------------
// 256 threads = 2 nodes/block; 128 threads per node, one float4 (4 feats) per thread.
__global__ __launch_bounds__(256) void gather_kernel(
    const float* __restrict__ hp, const int* __restrict__ row_start,
    const int* __restrict__ csr_src, const float* __restrict__ din,
    const float* __restrict__ bias, float* __restrict__ out) {
  const int node = blockIdx.x * 2 + (threadIdx.x >> 7);
  if (node >= N_NODES) return;
  const int lane4 = (threadIdx.x & 127) * 4;

  const int beg = row_start[node];
  const int end = row_start[node + 1];

  float4 acc = make_float4(0.f, 0.f, 0.f, 0.f);
  int e = beg;
  for (; e + 2 <= end; e += 2) {
    const int s0 = csr_src[e];
    const int s1 = csr_src[e + 1];
    const float4 v0 = *(const float4*)(hp + (size_t)s0 * HID + lane4);
    const float4 v1 = *(const float4*)(hp + (size_t)s1 * HID + lane4);
    acc.x += v0.x + v1.x; acc.y += v0.y + v1.y;
    acc.z += v0.z + v1.z; acc.w += v0.w + v1.w;
  }
  if (e < end) {
    const int s0 = csr_src[e];
    const float4 v0 = *(const float4*)(hp + (size_t)s0 * HID + lane4);
    acc.x += v0.x; acc.y += v0.y; acc.z += v0.z; acc.w += v0.w;
  }

  const float sc = din[node];
  const float4 b = *(const float4*)(bias + lane4);
  float4 r;
  r.x = fmaxf(acc.x * sc + b.x, 0.f);
  r.y = fmaxf(acc.y * sc + b.y, 0.f);
  r.z = fmaxf(acc.z * sc + b.z, 0.f);
  r.w = fmaxf(acc.w * sc + b.w, 0.f);
  *(float4*)(out + (size_t)node * HID + lane4) = r;
}

// ---------------- graph boundaries from sorted graph_ids ----------------
__global__ void bounds_kernel(const int* __restrict__ gid, int* __restrict__ gstart) {
  int i = blockIdx.x * blockDim.x + threadIdx.x;
  if (i >= N_NODES) return;
  const int g = gid[i];
  const int gp = (i == 0) ? -1 : gid[i - 1];
  for (int k = gp + 1; k <= g; k++) gstart[k] = i;
  if (i == N_NODES - 1) {
    for (int k = g + 1; k <= N_GRAPHS; k++) gstart[k] = N_NODES;
  }
}

// ---------------- segmented mean pool: grid (G, 4), block 128, 1 float/thread ----------------
__global__ __launch_bounds__(128) void pool_kernel(
    const float* __restrict__ h, const int* __restrict__ gstart, float* __restrict__ hg) {
  const int g = blockIdx.x;
  const int col = blockIdx.y * 128 + threadIdx.x;
  const int beg = gstart[g], end = gstart[g + 1];
  float acc = 0.f;
  int n = beg;
  for (; n + 4 <= end; n += 4) {
    float a0 = h[(size_t)(n + 0) * HID + col];
    float a1 = h[(size_t)(n + 1) * HID + col];
    float a2 = h[(size_t)(n + 2) * HID + col];
    float a3 = h[(size_t)(n + 3) * HID + col];
    acc += (a0 + a1) + (a2 + a3);
  }
  for (; n < end; n++) acc += h[(size_t)n * HID + col];
  const float inv = 1.0f / fmaxf((float)(end - beg), 1.0f);
  hg[(size_t)g * HID + col] = acc * inv;
}

// ---------------- small dense: out[G,N] = act(in[G,K] @ W[K,N] + b[N]) ----------------
__global__ void dense_kernel(const float* __restrict__ in, const float* __restrict__ W,
                             const float* __restrict__ b, float* __restrict__ out,
                             int G, int K, int N, int relu) {
  int idx = blockIdx.x * blockDim.x + threadIdx.x;
  if (idx >= G * N) return;
  int g = idx / N, n = idx % N;
  float acc = b[n];
  for (int k = 0; k < K; k++) acc += in[(size_t)g * K + k] * W[(size_t)k * N + n];
  if (relu) acc = fmaxf(acc, 0.0f);
  out[idx] = acc;
}

extern "C" void kernel_launch(void* const* d_in, const int* in_sizes, int n_in,
                              void* d_out, int out_size, void* d_ws, size_t ws_size,
                              hipStream_t stream) {
  const float* x   = (const float*)d_in[0];
  const int*   src = (const int*)d_in[1];
  const int*   dst = (const int*)d_in[2];
  const int*   gid = (const int*)d_in[3];
  const float* W1  = (const float*)d_in[4];  const float* b1  = (const float*)d_in[5];
  const float* W2  = (const float*)d_in[6];  const float* b2  = (const float*)d_in[7];
  const float* W3  = (const float*)d_in[8];  const float* b3  = (const float*)d_in[9];
  const float* Wc1 = (const float*)d_in[10]; const float* bc1 = (const float*)d_in[11];
  const float* Wc2 = (const float*)d_in[12]; const float* bc2 = (const float*)d_in[13];
  const float* Wc3 = (const float*)d_in[14]; const float* bc3 = (const float*)d_in[15];
  float* out = (float*)d_out;

  char* ws = (char*)d_ws;
  float* bufA = (float*)ws;                               // [N_NODES, HID]
  float* bufB = bufA + (size_t)N_NODES * HID;             // [N_NODES, HID]
  float* dosq = bufB + (size_t)N_NODES * HID;             // [N_NODES]
  float* disq = dosq + N_NODES;                           // [N_NODES]
  float* hg   = disq + N_NODES;                           // [G, HID]
  float* m1   = hg + N_GRAPHS * HID;                      // [G, HID]
  float* m2   = m1 + N_GRAPHS * HID;                      // [G, HID]
  int* deg_out_i = (int*)(m2 + N_GRAPHS * HID);           // [N_NODES]
  int* deg_in_i  = deg_out_i + N_NODES;                   // [N_NODES]
  int* cursor    = deg_in_i + N_NODES;                    // [N_NODES]
  int* row_start = cursor + N_NODES;                      // [N_NODES+1]
  int* gstart    = row_start + (N_NODES + 1);             // [N_GRAPHS+1]
  int* csr_src   = gstart + (N_GRAPHS + 1);               // [N_EDGES]

  // ---- CSR + degree setup (edges static across layers: build once) ----
  hipMemsetAsync(deg_out_i, 0, 3 * N_NODES * sizeof(int), stream);  // degs + cursor
  deg_kernel<<<(N_EDGES + 255) / 256, 256, 0, stream>>>(src, dst, deg_out_i, deg_in_i, N_EDGES);
  isqrt_from_int<<<(2 * N_NODES + 255) / 256, 256, 0, stream>>>(deg_out_i, dosq, 2 * N_NODES);
  scan_kernel<<<1, 1024, 0, stream>>>(deg_in_i, row_start, N_NODES);
  csr_fill<<<(N_EDGES + 255) / 256, 256, 0, stream>>>(src, dst, row_start, cursor, csr_src, N_EDGES);
  bounds_kernel<<<(N_NODES + 255) / 256, 256, 0, stream>>>(gid, gstart);

  const dim3 ggrid((N_NODES + BM - 1) / BM, HID / BN);
  const int gat_blocks = (N_NODES + 1) / 2;

  // ---- conv layer 1 ----
  gemm_scaled<<<ggrid, 256, 0, stream>>>(x, W1, dosq, bufB, N_NODES, IN_DIM, HID);
  gather_kernel<<<gat_blocks, 256, 0, stream>>>(bufB, row_start, csr_src, disq, b1, bufA);

  // ---- conv layer 2 ----
  gemm_scaled<<<ggrid, 256, 0, stream>>>(bufA, W2, dosq, bufB, N_NODES, HID, HID);
  gather_kernel<<<gat_blocks, 256, 0, stream>>>(bufB, row_start, csr_src, disq, b2, bufA);

  // ---- conv layer 3 ----
  gemm_scaled<<<ggrid, 256, 0, stream>>>(bufA, W3, dosq, bufB, N_NODES, HID, HID);
  gather_kernel<<<gat_blocks, 256, 0, stream>>>(bufB, row_start, csr_src, disq, b3, bufA);

  // ---- mean pooling (segmented, no atomics) ----
  pool_kernel<<<dim3(N_GRAPHS, HID / 128), 128, 0, stream>>>(bufA, gstart, hg);

  // ---- classifier MLP ----
  dense_kernel<<<(N_GRAPHS * HID + 255) / 256, 256, 0, stream>>>(hg, Wc1, bc1, m1, N_GRAPHS, HID, HID, 1);
  dense_kernel<<<(N_GRAPHS * HID + 255) / 256, 256, 0, stream>>>(m1, Wc2, bc2, m2, N_GRAPHS, HID, HID, 1);
  dense_kernel<<<(N_GRAPHS * N_CLASSES + 255) / 256, 256, 0, stream>>>(m2, Wc3, bc3, out, N_GRAPHS, HID, N_CLASSES, 0);
}

// Round 3
// 1025.163 us; speedup vs baseline: 4.4520x; 1.1359x over previous
//
#include <hip/hip_runtime.h>

#define N_NODES 20000
#define N_EDGES 160000
#define N_GRAPHS 64
#define IN_DIM 128
#define HID 512
#define N_CLASSES 16

// ---------------- degrees (int) ----------------
__global__ void deg_kernel(const int* __restrict__ src, const int* __restrict__ dst,
                           int* __restrict__ dout, int* __restrict__ din, int E) {
  int e = blockIdx.x * blockDim.x + threadIdx.x;
  if (e < E) {
    atomicAdd(dout + src[e], 1);
    atomicAdd(din + dst[e], 1);
  }
}

__global__ void isqrt_from_int(const int* __restrict__ di, float* __restrict__ f, int n) {
  int i = blockIdx.x * blockDim.x + threadIdx.x;
  if (i < n) f[i] = rsqrtf(fmaxf((float)di[i], 1.0f));
}

// ---------------- single-block exclusive scan ----------------
__global__ __launch_bounds__(1024) void scan_kernel(const int* __restrict__ deg,
                                                    int* __restrict__ row_start, int n) {
  __shared__ int s[1024];
  __shared__ int carry;
  if (threadIdx.x == 0) { carry = 0; row_start[0] = 0; }
  __syncthreads();
  for (int base = 0; base < n; base += 1024) {
    const int i = base + threadIdx.x;
    s[threadIdx.x] = (i < n) ? deg[i] : 0;
    __syncthreads();
#pragma unroll
    for (int off = 1; off < 1024; off <<= 1) {
      int t = (threadIdx.x >= off) ? s[threadIdx.x - off] : 0;
      __syncthreads();
      s[threadIdx.x] += t;
      __syncthreads();
    }
    const int c = carry;
    if (i < n) row_start[i + 1] = c + s[threadIdx.x];
    __syncthreads();
    if (threadIdx.x == 0) carry = c + s[1023];
    __syncthreads();
  }
}

// ---------------- CSR fill ----------------
__global__ void csr_fill(const int* __restrict__ src, const int* __restrict__ dst,
                         const int* __restrict__ row_start, int* __restrict__ cursor,
                         int* __restrict__ csr_src, int E) {
  int e = blockIdx.x * blockDim.x + threadIdx.x;
  if (e < E) {
    const int d = dst[e];
    const int pos = atomicAdd(cursor + d, 1);
    csr_src[row_start[d] + pos] = src[e];
  }
}

// ---------------- scaled SGEMM: C[M,N] = (scale[m]*A[m,:]) @ W[K,N] ----------------
// 128x128 tile, BK=8, 256 threads, 8x8 micro-tile, As transposed, b128 LDS reads.
#define TBM 128
#define TBN 128
#define TBK 8
__global__ __launch_bounds__(256) void gemm_scaled(
    const float* __restrict__ A, const float* __restrict__ W,
    const float* __restrict__ scale, float* __restrict__ C,
    int M, int K, int N) {
  __shared__ float As[TBK][TBM + 4];   // transposed: As[k][m]
  __shared__ float Bs[TBK][TBN + 4];

  const int t  = threadIdx.x;
  const int tx = t & 15;         // col micro index
  const int ty = t >> 4;         // row micro index
  const int col0 = blockIdx.x * TBN;
  const int row0 = blockIdx.y * TBM;

  // A staging: 128 rows x 8 k, one float4/thread
  const int arow = t >> 1;             // 0..127
  const int ak   = (t & 1) * 4;        // 0 or 4
  // B staging: 8 rows x 128 cols, one float4/thread
  const int brow = t >> 5;             // 0..7
  const int bcol = (t & 31) * 4;       // 0..124

  const int garow = row0 + arow;
  const bool arow_ok = garow < M;
  const float sc = arow_ok ? scale[garow] : 0.0f;
  const float* aptr = A + (size_t)(arow_ok ? garow : 0) * K + ak;
  const float* bptr = W + (size_t)brow * N + col0 + bcol;

  float acc[8][8] = {};

  for (int k0 = 0; k0 < K; k0 += TBK) {
    float4 av = arow_ok ? *(const float4*)(aptr + k0) : make_float4(0.f, 0.f, 0.f, 0.f);
    float4 bv = *(const float4*)(bptr + (size_t)k0 * N);
    As[ak + 0][arow] = av.x * sc;
    As[ak + 1][arow] = av.y * sc;
    As[ak + 2][arow] = av.z * sc;
    As[ak + 3][arow] = av.w * sc;
    *(float4*)&Bs[brow][bcol] = bv;
    __syncthreads();

#pragma unroll
    for (int kk = 0; kk < TBK; kk++) {
      const float4 a0 = *(const float4*)&As[kk][ty * 8];
      const float4 a1 = *(const float4*)&As[kk][ty * 8 + 4];
      const float4 b0 = *(const float4*)&Bs[kk][tx * 8];
      const float4 b1 = *(const float4*)&Bs[kk][tx * 8 + 4];
      const float a[8] = {a0.x, a0.y, a0.z, a0.w, a1.x, a1.y, a1.z, a1.w};
      const float b[8] = {b0.x, b0.y, b0.z, b0.w, b1.x, b1.y, b1.z, b1.w};
#pragma unroll
      for (int i = 0; i < 8; i++)
#pragma unroll
        for (int j = 0; j < 8; j++)
          acc[i][j] += a[i] * b[j];
    }
    __syncthreads();
  }

#pragma unroll
  for (int i = 0; i < 8; i++) {
    const int r = row0 + ty * 8 + i;
    if (r < M) {
      float* cp = C + (size_t)r * N + col0 + tx * 8;
      *(float4*)cp       = make_float4(acc[i][0], acc[i][1], acc[i][2], acc[i][3]);
      *(float4*)(cp + 4) = make_float4(acc[i][4], acc[i][5], acc[i][6], acc[i][7]);
    }
  }
}

// ---------------- CSR gather-aggregate, fused din_isqrt + bias + relu ----------------
__global__ __launch_bounds__(256) void gather_kernel(
    const float* __restrict__ hp, const int* __restrict__ row_start,
    const int* __restrict__ csr_src, const float* __restrict__ din,
    const float* __restrict__ bias, float* __restrict__ out) {
  const int node = blockIdx.x * 2 + (threadIdx.x >> 7);
  if (node >= N_NODES) return;
  const int lane4 = (threadIdx.x & 127) * 4;

  const int beg = row_start[node];
  const int end = row_start[node + 1];

  float4 acc = make_float4(0.f, 0.f, 0.f, 0.f);
  int e = beg;
  for (; e + 2 <= end; e += 2) {
    const int s0 = csr_src[e];
    const int s1 = csr_src[e + 1];
    const float4 v0 = *(const float4*)(hp + (size_t)s0 * HID + lane4);
    const float4 v1 = *(const float4*)(hp + (size_t)s1 * HID + lane4);
    acc.x += v0.x + v1.x; acc.y += v0.y + v1.y;
    acc.z += v0.z + v1.z; acc.w += v0.w + v1.w;
  }
  if (e < end) {
    const int s0 = csr_src[e];
    const float4 v0 = *(const float4*)(hp + (size_t)s0 * HID + lane4);
    acc.x += v0.x; acc.y += v0.y; acc.z += v0.z; acc.w += v0.w;
  }

  const float sc = din[node];
  const float4 b = *(const float4*)(bias + lane4);
  float4 r;
  r.x = fmaxf(acc.x * sc + b.x, 0.f);
  r.y = fmaxf(acc.y * sc + b.y, 0.f);
  r.z = fmaxf(acc.z * sc + b.z, 0.f);
  r.w = fmaxf(acc.w * sc + b.w, 0.f);
  *(float4*)(out + (size_t)node * HID + lane4) = r;
}

// ---------------- graph boundaries from sorted graph_ids ----------------
__global__ void bounds_kernel(const int* __restrict__ gid, int* __restrict__ gstart) {
  int i = blockIdx.x * blockDim.x + threadIdx.x;
  if (i >= N_NODES) return;
  const int g = gid[i];
  const int gp = (i == 0) ? -1 : gid[i - 1];
  for (int k = gp + 1; k <= g; k++) gstart[k] = i;
  if (i == N_NODES - 1) {
    for (int k = g + 1; k <= N_GRAPHS; k++) gstart[k] = N_NODES;
  }
}

// ---------------- segmented mean pool ----------------
__global__ __launch_bounds__(128) void pool_kernel(
    const float* __restrict__ h, const int* __restrict__ gstart, float* __restrict__ hg) {
  const int g = blockIdx.x;
  const int col = blockIdx.y * 128 + threadIdx.x;
  const int beg = gstart[g], end = gstart[g + 1];
  float acc = 0.f;
  int n = beg;
  for (; n + 4 <= end; n += 4) {
    float a0 = h[(size_t)(n + 0) * HID + col];
    float a1 = h[(size_t)(n + 1) * HID + col];
    float a2 = h[(size_t)(n + 2) * HID + col];
    float a3 = h[(size_t)(n + 3) * HID + col];
    acc += (a0 + a1) + (a2 + a3);
  }
  for (; n < end; n++) acc += h[(size_t)n * HID + col];
  const float inv = 1.0f / fmaxf((float)(end - beg), 1.0f);
  hg[(size_t)g * HID + col] = acc * inv;
}

// ---------------- small dense ----------------
__global__ void dense_kernel(const float* __restrict__ in, const float* __restrict__ W,
                             const float* __restrict__ b, float* __restrict__ out,
                             int G, int K, int N, int relu) {
  int idx = blockIdx.x * blockDim.x + threadIdx.x;
  if (idx >= G * N) return;
  int g = idx / N, n = idx % N;
  float acc = b[n];
  for (int k = 0; k < K; k++) acc += in[(size_t)g * K + k] * W[(size_t)k * N + n];
  if (relu) acc = fmaxf(acc, 0.0f);
  out[idx] = acc;
}

extern "C" void kernel_launch(void* const* d_in, const int* in_sizes, int n_in,
                              void* d_out, int out_size, void* d_ws, size_t ws_size,
                              hipStream_t stream) {
  const float* x   = (const float*)d_in[0];
  const int*   src = (const int*)d_in[1];
  const int*   dst = (const int*)d_in[2];
  const int*   gid = (const int*)d_in[3];
  const float* W1  = (const float*)d_in[4];  const float* b1  = (const float*)d_in[5];
  const float* W2  = (const float*)d_in[6];  const float* b2  = (const float*)d_in[7];
  const float* W3  = (const float*)d_in[8];  const float* b3  = (const float*)d_in[9];
  const float* Wc1 = (const float*)d_in[10]; const float* bc1 = (const float*)d_in[11];
  const float* Wc2 = (const float*)d_in[12]; const float* bc2 = (const float*)d_in[13];
  const float* Wc3 = (const float*)d_in[14]; const float* bc3 = (const float*)d_in[15];
  float* out = (float*)d_out;

  char* ws = (char*)d_ws;
  float* bufA = (float*)ws;                               // [N_NODES, HID]
  float* bufB = bufA + (size_t)N_NODES * HID;             // [N_NODES, HID]
  float* dosq = bufB + (size_t)N_NODES * HID;             // [N_NODES]
  float* disq = dosq + N_NODES;                           // [N_NODES]
  float* hg   = disq + N_NODES;                           // [G, HID]
  float* m1   = hg + N_GRAPHS * HID;                      // [G, HID]
  float* m2   = m1 + N_GRAPHS * HID;                      // [G, HID]
  int* deg_out_i = (int*)(m2 + N_GRAPHS * HID);           // [N_NODES]
  int* deg_in_i  = deg_out_i + N_NODES;                   // [N_NODES]
  int* cursor    = deg_in_i + N_NODES;                    // [N_NODES]
  int* row_start = cursor + N_NODES;                      // [N_NODES+1]
  int* gstart    = row_start + (N_NODES + 1);             // [N_GRAPHS+1]
  int* csr_src   = gstart + (N_GRAPHS + 1);               // [N_EDGES]

  // ---- CSR + degree setup ----
  hipMemsetAsync(deg_out_i, 0, 3 * N_NODES * sizeof(int), stream);
  deg_kernel<<<(N_EDGES + 255) / 256, 256, 0, stream>>>(src, dst, deg_out_i, deg_in_i, N_EDGES);
  isqrt_from_int<<<(2 * N_NODES + 255) / 256, 256, 0, stream>>>(deg_out_i, dosq, 2 * N_NODES);
  scan_kernel<<<1, 1024, 0, stream>>>(deg_in_i, row_start, N_NODES);
  csr_fill<<<(N_EDGES + 255) / 256, 256, 0, stream>>>(src, dst, row_start, cursor, csr_src, N_EDGES);
  bounds_kernel<<<(N_NODES + 255) / 256, 256, 0, stream>>>(gid, gstart);

  // grid: x = col tiles (adjacent blocks share A rows -> L2 reuse), y = row tiles
  const dim3 ggrid(HID / TBN, (N_NODES + TBM - 1) / TBM);
  const int gat_blocks = (N_NODES + 1) / 2;

  // ---- conv layer 1 ----
  gemm_scaled<<<ggrid, 256, 0, stream>>>(x, W1, dosq, bufB, N_NODES, IN_DIM, HID);
  gather_kernel<<<gat_blocks, 256, 0, stream>>>(bufB, row_start, csr_src, disq, b1, bufA);

  // ---- conv layer 2 ----
  gemm_scaled<<<ggrid, 256, 0, stream>>>(bufA, W2, dosq, bufB, N_NODES, HID, HID);
  gather_kernel<<<gat_blocks, 256, 0, stream>>>(bufB, row_start, csr_src, disq, b2, bufA);

  // ---- conv layer 3 ----
  gemm_scaled<<<ggrid, 256, 0, stream>>>(bufA, W3, dosq, bufB, N_NODES, HID, HID);
  gather_kernel<<<gat_blocks, 256, 0, stream>>>(bufB, row_start, csr_src, disq, b3, bufA);

  // ---- mean pooling ----
  pool_kernel<<<dim3(N_GRAPHS, HID / 128), 128, 0, stream>>>(bufA, gstart, hg);

  // ---- classifier MLP ----
  dense_kernel<<<(N_GRAPHS * HID + 255) / 256, 256, 0, stream>>>(hg, Wc1, bc1, m1, N_GRAPHS, HID, HID, 1);
  dense_kernel<<<(N_GRAPHS * HID + 255) / 256, 256, 0, stream>>>(m1, Wc2, bc2, m2, N_GRAPHS, HID, HID, 1);
  dense_kernel<<<(N_GRAPHS * N_CLASSES + 255) / 256, 256, 0, stream>>>(m2, Wc3, bc3, out, N_GRAPHS, HID, N_CLASSES, 0);
}

// Round 4
// 735.030 us; speedup vs baseline: 6.2093x; 1.3947x over previous
//
#include <hip/hip_runtime.h>

#define N_NODES 20000
#define N_EDGES 160000
#define N_GRAPHS 64
#define IN_DIM 128
#define HID 512
#define N_CLASSES 16

typedef unsigned short u16;
typedef short bf16x8 __attribute__((ext_vector_type(8)));
typedef float f32x4 __attribute__((ext_vector_type(4)));

// round-to-nearest-even fp32 -> bf16 bits
__device__ __forceinline__ u16 bf16_rn(float x) {
  unsigned u = __float_as_uint(x);
  unsigned r = u + 0x7FFFu + ((u >> 16) & 1u);
  return (u16)(r >> 16);
}

// ---------------- degrees (int) ----------------
__global__ void deg_kernel(const int* __restrict__ src, const int* __restrict__ dst,
                           int* __restrict__ dout, int* __restrict__ din, int E) {
  int e = blockIdx.x * blockDim.x + threadIdx.x;
  if (e < E) {
    atomicAdd(dout + src[e], 1);
    atomicAdd(din + dst[e], 1);
  }
}

__global__ void isqrt_from_int(const int* __restrict__ di, float* __restrict__ f, int n) {
  int i = blockIdx.x * blockDim.x + threadIdx.x;
  if (i < n) f[i] = rsqrtf(fmaxf((float)di[i], 1.0f));
}

// ---------------- single-block exclusive scan ----------------
__global__ __launch_bounds__(1024) void scan_kernel(const int* __restrict__ deg,
                                                    int* __restrict__ row_start, int n) {
  __shared__ int s[1024];
  __shared__ int carry;
  if (threadIdx.x == 0) { carry = 0; row_start[0] = 0; }
  __syncthreads();
  for (int base = 0; base < n; base += 1024) {
    const int i = base + threadIdx.x;
    s[threadIdx.x] = (i < n) ? deg[i] : 0;
    __syncthreads();
#pragma unroll
    for (int off = 1; off < 1024; off <<= 1) {
      int t = (threadIdx.x >= off) ? s[threadIdx.x - off] : 0;
      __syncthreads();
      s[threadIdx.x] += t;
      __syncthreads();
    }
    const int c = carry;
    if (i < n) row_start[i + 1] = c + s[threadIdx.x];
    __syncthreads();
    if (threadIdx.x == 0) carry = c + s[1023];
    __syncthreads();
  }
}

// ---------------- CSR fill ----------------
__global__ void csr_fill(const int* __restrict__ src, const int* __restrict__ dst,
                         const int* __restrict__ row_start, int* __restrict__ cursor,
                         int* __restrict__ csr_src, int E) {
  int e = blockIdx.x * blockDim.x + threadIdx.x;
  if (e < E) {
    const int d = dst[e];
    const int pos = atomicAdd(cursor + d, 1);
    csr_src[row_start[d] + pos] = src[e];
  }
}

// ---------------- weight prep: W[K][N] fp32 -> Wt_hi/lo[N][K] bf16 ----------------
__global__ void wprep_kernel(const float* __restrict__ W, u16* __restrict__ th,
                             u16* __restrict__ tl, int K, int N) {
  int idx = blockIdx.x * blockDim.x + threadIdx.x;
  if (idx >= K * N) return;
  const int k = idx / N;
  const int n = idx - k * N;
  const float x = W[idx];
  const u16 hi = bf16_rn(x);
  const float hif = __uint_as_float((unsigned)hi << 16);
  const u16 lo = bf16_rn(x - hif);
  th[(size_t)n * K + k] = hi;
  tl[(size_t)n * K + k] = lo;
}

// ---------------- CSR gather: g = din[n] * sum_{s} dout[s]*h[s], write bf16 hi/lo planes ----------------
// width = 1<<wshift floats per node; cpn = 1<<cshift threads per node (cpn = width/4)
__global__ __launch_bounds__(256) void gather_split(
    const float* __restrict__ h, const int* __restrict__ row_start,
    const int* __restrict__ csr_src, const float* __restrict__ dosq,
    const float* __restrict__ disq, u16* __restrict__ gh, u16* __restrict__ gl,
    int wshift, int cshift) {
  const int npb = 256 >> cshift;
  const int node = blockIdx.x * npb + (threadIdx.x >> cshift);
  if (node >= N_NODES) return;
  const int lane4 = (threadIdx.x & ((1 << cshift) - 1)) * 4;

  const int beg = row_start[node];
  const int end = row_start[node + 1];

  float4 acc = make_float4(0.f, 0.f, 0.f, 0.f);
  for (int e = beg; e < end; e++) {
    const int s = csr_src[e];
    const float ds = dosq[s];
    const float4 v = *(const float4*)(h + ((size_t)s << wshift) + lane4);
    acc.x += ds * v.x; acc.y += ds * v.y;
    acc.z += ds * v.z; acc.w += ds * v.w;
  }
  const float di = disq[node];
  acc.x *= di; acc.y *= di; acc.z *= di; acc.w *= di;

  ushort4 vh, vl;
  float t;
  vh.x = bf16_rn(acc.x); t = acc.x - __uint_as_float((unsigned)vh.x << 16); vl.x = bf16_rn(t);
  vh.y = bf16_rn(acc.y); t = acc.y - __uint_as_float((unsigned)vh.y << 16); vl.y = bf16_rn(t);
  vh.z = bf16_rn(acc.z); t = acc.z - __uint_as_float((unsigned)vh.z << 16); vl.z = bf16_rn(t);
  vh.w = bf16_rn(acc.w); t = acc.w - __uint_as_float((unsigned)vh.w << 16); vl.w = bf16_rn(t);
  const size_t o = ((size_t)node << wshift) + lane4;
  *(ushort4*)(gh + o) = vh;
  *(ushort4*)(gl + o) = vl;
}

// ---------------- split-bf16 MFMA GEMM: C[M,512] = relu(A[M,K] @ Wt[512,K]^T + bias) ----------------
// A given as hi/lo bf16 planes [M][K]; Wt as hi/lo planes [N][K] (pre-transposed).
// 128x128 tile, 256 threads (4 waves 2x2), each wave 4x4 tiles of 16x16x32.
// 3 MFMAs per fragment pair: hi*hi + lo*hi + hi*lo (fp32-accurate to ~2^-18 rel).
#define GBK 32
#define LROW 40   // u16 per LDS row: 32 + 8 pad (80 B, multiple of 16 B; 2-way bank alias only)
__global__ __launch_bounds__(256) void gemm_mfma(
    const u16* __restrict__ Ah, const u16* __restrict__ Al,
    const u16* __restrict__ Bh, const u16* __restrict__ Bl,
    const float* __restrict__ bias, float* __restrict__ C,
    int M, int K) {
  __shared__ u16 sAh[128 * LROW];
  __shared__ u16 sAl[128 * LROW];
  __shared__ u16 sBh[128 * LROW];
  __shared__ u16 sBl[128 * LROW];

  const int t = threadIdx.x;
  const int col0 = blockIdx.x * 128;
  const int row0 = blockIdx.y * 128;

  const int lane = t & 63;
  const int wav  = t >> 6;
  const int wr = (wav >> 1) * 64;   // wave row offset
  const int wc = (wav & 1) * 64;    // wave col offset
  const int fm = lane & 15;         // A: row m / B: col n
  const int fq = lane >> 4;         // quad -> k = fq*8 + j

  // staging: per plane, 512 x int4; thread covers (row=t>>2, u=t&3) and (+64 rows)
  const int r0 = t >> 2;
  const int u0 = t & 3;

  f32x4 acc[4][4] = {};

  for (int k0 = 0; k0 < K; k0 += GBK) {
    __syncthreads();
    int4 va[2], vb[2], vc[2], vd[2];
#pragma unroll
    for (int rep = 0; rep < 2; rep++) {
      const int row = r0 + rep * 64;
      const int arow = row0 + row;
      const bool ok = arow < M;
      const size_t aoff = (size_t)arow * K + k0 + u0 * 8;
      va[rep] = ok ? *(const int4*)(Ah + aoff) : make_int4(0, 0, 0, 0);
      vb[rep] = ok ? *(const int4*)(Al + aoff) : make_int4(0, 0, 0, 0);
      const size_t boff = (size_t)(col0 + row) * K + k0 + u0 * 8;
      vc[rep] = *(const int4*)(Bh + boff);
      vd[rep] = *(const int4*)(Bl + boff);
    }
#pragma unroll
    for (int rep = 0; rep < 2; rep++) {
      const int ldso = (r0 + rep * 64) * LROW + u0 * 8;
      *(int4*)(sAh + ldso) = va[rep];
      *(int4*)(sAl + ldso) = vb[rep];
      *(int4*)(sBh + ldso) = vc[rep];
      *(int4*)(sBl + ldso) = vd[rep];
    }
    __syncthreads();

    bf16x8 fah[4], fal[4], fbh[4], fbl[4];
#pragma unroll
    for (int i = 0; i < 4; i++) {
      const int ar = (wr + i * 16 + fm) * LROW + fq * 8;
      fah[i] = *(const bf16x8*)(sAh + ar);
      fal[i] = *(const bf16x8*)(sAl + ar);
      const int br = (wc + i * 16 + fm) * LROW + fq * 8;
      fbh[i] = *(const bf16x8*)(sBh + br);
      fbl[i] = *(const bf16x8*)(sBl + br);
    }
#pragma unroll
    for (int j = 0; j < 4; j++)
#pragma unroll
      for (int i = 0; i < 4; i++) {
        acc[i][j] = __builtin_amdgcn_mfma_f32_16x16x32_bf16(fah[i], fbh[j], acc[i][j], 0, 0, 0);
        acc[i][j] = __builtin_amdgcn_mfma_f32_16x16x32_bf16(fal[i], fbh[j], acc[i][j], 0, 0, 0);
        acc[i][j] = __builtin_amdgcn_mfma_f32_16x16x32_bf16(fah[i], fbl[j], acc[i][j], 0, 0, 0);
      }
  }

  // epilogue: bias + relu; C/D layout: col = lane&15, row = fq*4 + reg
#pragma unroll
  for (int i = 0; i < 4; i++) {
#pragma unroll
    for (int r = 0; r < 4; r++) {
      const int grow = row0 + wr + i * 16 + fq * 4 + r;
      if (grow < M) {
#pragma unroll
        for (int j = 0; j < 4; j++) {
          const int gcol = col0 + wc + j * 16 + fm;
          const float v = acc[i][j][r] + bias[gcol];
          C[(size_t)grow * HID + gcol] = fmaxf(v, 0.0f);
        }
      }
    }
  }
}

// ---------------- graph boundaries from sorted graph_ids ----------------
__global__ void bounds_kernel(const int* __restrict__ gid, int* __restrict__ gstart) {
  int i = blockIdx.x * blockDim.x + threadIdx.x;
  if (i >= N_NODES) return;
  const int g = gid[i];
  const int gp = (i == 0) ? -1 : gid[i - 1];
  for (int k = gp + 1; k <= g; k++) gstart[k] = i;
  if (i == N_NODES - 1) {
    for (int k = g + 1; k <= N_GRAPHS; k++) gstart[k] = N_NODES;
  }
}

// ---------------- segmented mean pool ----------------
__global__ __launch_bounds__(128) void pool_kernel(
    const float* __restrict__ h, const int* __restrict__ gstart, float* __restrict__ hg) {
  const int g = blockIdx.x;
  const int col = blockIdx.y * 128 + threadIdx.x;
  const int beg = gstart[g], end = gstart[g + 1];
  float acc = 0.f;
  int n = beg;
  for (; n + 4 <= end; n += 4) {
    float a0 = h[(size_t)(n + 0) * HID + col];
    float a1 = h[(size_t)(n + 1) * HID + col];
    float a2 = h[(size_t)(n + 2) * HID + col];
    float a3 = h[(size_t)(n + 3) * HID + col];
    acc += (a0 + a1) + (a2 + a3);
  }
  for (; n < end; n++) acc += h[(size_t)n * HID + col];
  const float inv = 1.0f / fmaxf((float)(end - beg), 1.0f);
  hg[(size_t)g * HID + col] = acc * inv;
}

// ---------------- small dense ----------------
__global__ void dense_kernel(const float* __restrict__ in, const float* __restrict__ W,
                             const float* __restrict__ b, float* __restrict__ out,
                             int G, int K, int N, int relu) {
  int idx = blockIdx.x * blockDim.x + threadIdx.x;
  if (idx >= G * N) return;
  int g = idx / N, n = idx % N;
  float acc = b[n];
  for (int k = 0; k < K; k++) acc += in[(size_t)g * K + k] * W[(size_t)k * N + n];
  if (relu) acc = fmaxf(acc, 0.0f);
  out[idx] = acc;
}

extern "C" void kernel_launch(void* const* d_in, const int* in_sizes, int n_in,
                              void* d_out, int out_size, void* d_ws, size_t ws_size,
                              hipStream_t stream) {
  const float* x   = (const float*)d_in[0];
  const int*   src = (const int*)d_in[1];
  const int*   dst = (const int*)d_in[2];
  const int*   gid = (const int*)d_in[3];
  const float* W1  = (const float*)d_in[4];  const float* b1  = (const float*)d_in[5];
  const float* W2  = (const float*)d_in[6];  const float* b2  = (const float*)d_in[7];
  const float* W3  = (const float*)d_in[8];  const float* b3  = (const float*)d_in[9];
  const float* Wc1 = (const float*)d_in[10]; const float* bc1 = (const float*)d_in[11];
  const float* Wc2 = (const float*)d_in[12]; const float* bc2 = (const float*)d_in[13];
  const float* Wc3 = (const float*)d_in[14]; const float* bc3 = (const float*)d_in[15];
  float* out = (float*)d_out;

  char* p = (char*)d_ws;
  float* bufA = (float*)p;            p += (size_t)N_NODES * HID * 4;   // h fp32 [20000,512]
  u16* gh  = (u16*)p;                 p += (size_t)N_NODES * HID * 2;   // g hi plane
  u16* gl  = (u16*)p;                 p += (size_t)N_NODES * HID * 2;   // g lo plane
  u16* w1h = (u16*)p;                 p += (size_t)HID * IN_DIM * 2;
  u16* w1l = (u16*)p;                 p += (size_t)HID * IN_DIM * 2;
  u16* w2h = (u16*)p;                 p += (size_t)HID * HID * 2;
  u16* w2l = (u16*)p;                 p += (size_t)HID * HID * 2;
  u16* w3h = (u16*)p;                 p += (size_t)HID * HID * 2;
  u16* w3l = (u16*)p;                 p += (size_t)HID * HID * 2;
  float* dosq = (float*)p;            p += N_NODES * 4;
  float* disq = (float*)p;            p += N_NODES * 4;
  float* hg = (float*)p;              p += N_GRAPHS * HID * 4;
  float* m1 = (float*)p;              p += N_GRAPHS * HID * 4;
  float* m2 = (float*)p;              p += N_GRAPHS * HID * 4;
  int* deg_out_i = (int*)p;           p += N_NODES * 4;
  int* deg_in_i  = (int*)p;           p += N_NODES * 4;
  int* cursor    = (int*)p;           p += N_NODES * 4;
  int* row_start = (int*)p;           p += (N_NODES + 1) * 4;
  int* gstart    = (int*)p;           p += (N_GRAPHS + 1) * 4;
  int* csr_src   = (int*)p;

  // ---- CSR + degree + weight prep ----
  hipMemsetAsync(deg_out_i, 0, 3 * N_NODES * sizeof(int), stream);
  deg_kernel<<<(N_EDGES + 255) / 256, 256, 0, stream>>>(src, dst, deg_out_i, deg_in_i, N_EDGES);
  isqrt_from_int<<<(2 * N_NODES + 255) / 256, 256, 0, stream>>>(deg_out_i, dosq, 2 * N_NODES);
  scan_kernel<<<1, 1024, 0, stream>>>(deg_in_i, row_start, N_NODES);
  csr_fill<<<(N_EDGES + 255) / 256, 256, 0, stream>>>(src, dst, row_start, cursor, csr_src, N_EDGES);
  bounds_kernel<<<(N_NODES + 255) / 256, 256, 0, stream>>>(gid, gstart);
  wprep_kernel<<<(IN_DIM * HID + 255) / 256, 256, 0, stream>>>(W1, w1h, w1l, IN_DIM, HID);
  wprep_kernel<<<(HID * HID + 255) / 256, 256, 0, stream>>>(W2, w2h, w2l, HID, HID);
  wprep_kernel<<<(HID * HID + 255) / 256, 256, 0, stream>>>(W3, w3h, w3l, HID, HID);

  const dim3 ggrid(HID / 128, (N_NODES + 127) / 128);  // (4, 157)
  const int gat128 = (N_NODES + 7) / 8;    // width 128: 8 nodes/block
  const int gat512 = (N_NODES + 1) / 2;    // width 512: 2 nodes/block

  // ---- layer 1: gather x (width 128) -> GEMM K=128 ----
  gather_split<<<gat128, 256, 0, stream>>>(x, row_start, csr_src, dosq, disq, gh, gl, 7, 5);
  gemm_mfma<<<ggrid, 256, 0, stream>>>(gh, gl, w1h, w1l, b1, bufA, N_NODES, IN_DIM);

  // ---- layer 2 ----
  gather_split<<<gat512, 256, 0, stream>>>(bufA, row_start, csr_src, dosq, disq, gh, gl, 9, 7);
  gemm_mfma<<<ggrid, 256, 0, stream>>>(gh, gl, w2h, w2l, b2, bufA, N_NODES, HID);

  // ---- layer 3 ----
  gather_split<<<gat512, 256, 0, stream>>>(bufA, row_start, csr_src, dosq, disq, gh, gl, 9, 7);
  gemm_mfma<<<ggrid, 256, 0, stream>>>(gh, gl, w3h, w3l, b3, bufA, N_NODES, HID);

  // ---- mean pooling ----
  pool_kernel<<<dim3(N_GRAPHS, HID / 128), 128, 0, stream>>>(bufA, gstart, hg);

  // ---- classifier MLP ----
  dense_kernel<<<(N_GRAPHS * HID + 255) / 256, 256, 0, stream>>>(hg, Wc1, bc1, m1, N_GRAPHS, HID, HID, 1);
  dense_kernel<<<(N_GRAPHS * HID + 255) / 256, 256, 0, stream>>>(m1, Wc2, bc2, m2, N_GRAPHS, HID, HID, 1);
  dense_kernel<<<(N_GRAPHS * N_CLASSES + 255) / 256, 256, 0, stream>>>(m2, Wc3, bc3, out, N_GRAPHS, HID, N_CLASSES, 0);
}

// Round 5
// 454.900 us; speedup vs baseline: 10.0330x; 1.6158x over previous
//
#include <hip/hip_runtime.h>

#define N_NODES 20000
#define N_EDGES 160000
#define N_GRAPHS 64
#define IN_DIM 128
#define HID 512
#define N_CLASSES 16

typedef unsigned short u16;
typedef short bf16x8 __attribute__((ext_vector_type(8)));
typedef float f32x4 __attribute__((ext_vector_type(4)));

// round-to-nearest-even fp32 -> bf16 bits
__device__ __forceinline__ u16 bf16_rn(float x) {
  unsigned u = __float_as_uint(x);
  unsigned r = u + 0x7FFFu + ((u >> 16) & 1u);
  return (u16)(r >> 16);
}

// ---------------- degrees (int) ----------------
__global__ void deg_kernel(const int* __restrict__ src, const int* __restrict__ dst,
                           int* __restrict__ dout, int* __restrict__ din, int E) {
  int e = blockIdx.x * blockDim.x + threadIdx.x;
  if (e < E) {
    atomicAdd(dout + src[e], 1);
    atomicAdd(din + dst[e], 1);
  }
}

__global__ void isqrt_from_int(const int* __restrict__ di, float* __restrict__ f, int n) {
  int i = blockIdx.x * blockDim.x + threadIdx.x;
  if (i < n) f[i] = rsqrtf(fmaxf((float)di[i], 1.0f));
}

// ---------------- single-block exclusive scan ----------------
__global__ __launch_bounds__(1024) void scan_kernel(const int* __restrict__ deg,
                                                    int* __restrict__ row_start, int n) {
  __shared__ int s[1024];
  __shared__ int carry;
  if (threadIdx.x == 0) { carry = 0; row_start[0] = 0; }
  __syncthreads();
  for (int base = 0; base < n; base += 1024) {
    const int i = base + threadIdx.x;
    s[threadIdx.x] = (i < n) ? deg[i] : 0;
    __syncthreads();
#pragma unroll
    for (int off = 1; off < 1024; off <<= 1) {
      int t = (threadIdx.x >= off) ? s[threadIdx.x - off] : 0;
      __syncthreads();
      s[threadIdx.x] += t;
      __syncthreads();
    }
    const int c = carry;
    if (i < n) row_start[i + 1] = c + s[threadIdx.x];
    __syncthreads();
    if (threadIdx.x == 0) carry = c + s[1023];
    __syncthreads();
  }
}

// ---------------- CSR fill ----------------
__global__ void csr_fill(const int* __restrict__ src, const int* __restrict__ dst,
                         const int* __restrict__ row_start, int* __restrict__ cursor,
                         int* __restrict__ csr_src, int E) {
  int e = blockIdx.x * blockDim.x + threadIdx.x;
  if (e < E) {
    const int d = dst[e];
    const int pos = atomicAdd(cursor + d, 1);
    csr_src[row_start[d] + pos] = src[e];
  }
}

// ---------------- weight prep: W[K][N] fp32 -> Wt_hi/lo[N][K] bf16 ----------------
__global__ void wprep_kernel(const float* __restrict__ W, u16* __restrict__ th,
                             u16* __restrict__ tl, int K, int N) {
  int idx = blockIdx.x * blockDim.x + threadIdx.x;
  if (idx >= K * N) return;
  const int k = idx / N;
  const int n = idx - k * N;
  const float x = W[idx];
  const u16 hi = bf16_rn(x);
  const float hif = __uint_as_float((unsigned)hi << 16);
  const u16 lo = bf16_rn(x - hif);
  th[(size_t)n * K + k] = hi;
  tl[(size_t)n * K + k] = lo;
}

// ---------------- CSR gather: g = din[n] * sum_{s} dout[s]*h[s], write bf16 hi/lo planes ----------------
__global__ __launch_bounds__(256) void gather_split(
    const float* __restrict__ h, const int* __restrict__ row_start,
    const int* __restrict__ csr_src, const float* __restrict__ dosq,
    const float* __restrict__ disq, u16* __restrict__ gh, u16* __restrict__ gl,
    int wshift, int cshift) {
  const int npb = 256 >> cshift;
  const int node = blockIdx.x * npb + (threadIdx.x >> cshift);
  if (node >= N_NODES) return;
  const int lane4 = (threadIdx.x & ((1 << cshift) - 1)) * 4;

  const int beg = row_start[node];
  const int end = row_start[node + 1];

  float4 acc = make_float4(0.f, 0.f, 0.f, 0.f);
  for (int e = beg; e < end; e++) {
    const int s = csr_src[e];
    const float ds = dosq[s];
    const float4 v = *(const float4*)(h + ((size_t)s << wshift) + lane4);
    acc.x += ds * v.x; acc.y += ds * v.y;
    acc.z += ds * v.z; acc.w += ds * v.w;
  }
  const float di = disq[node];
  acc.x *= di; acc.y *= di; acc.z *= di; acc.w *= di;

  ushort4 vh, vl;
  float t;
  vh.x = bf16_rn(acc.x); t = acc.x - __uint_as_float((unsigned)vh.x << 16); vl.x = bf16_rn(t);
  vh.y = bf16_rn(acc.y); t = acc.y - __uint_as_float((unsigned)vh.y << 16); vl.y = bf16_rn(t);
  vh.z = bf16_rn(acc.z); t = acc.z - __uint_as_float((unsigned)vh.z << 16); vl.z = bf16_rn(t);
  vh.w = bf16_rn(acc.w); t = acc.w - __uint_as_float((unsigned)vh.w << 16); vl.w = bf16_rn(t);
  const size_t o = ((size_t)node << wshift) + lane4;
  *(ushort4*)(gh + o) = vh;
  *(ushort4*)(gl + o) = vl;
}

// ---------------- split-bf16 MFMA GEMM: C[M,512] = relu(A[M,K] @ Wt[512,K]^T + bias) ----------------
#define GBK 32
#define LROW 40
__global__ __launch_bounds__(256) void gemm_mfma(
    const u16* __restrict__ Ah, const u16* __restrict__ Al,
    const u16* __restrict__ Bh, const u16* __restrict__ Bl,
    const float* __restrict__ bias, float* __restrict__ C,
    int M, int K) {
  __shared__ u16 sAh[128 * LROW];
  __shared__ u16 sAl[128 * LROW];
  __shared__ u16 sBh[128 * LROW];
  __shared__ u16 sBl[128 * LROW];

  const int t = threadIdx.x;
  const int col0 = blockIdx.x * 128;
  const int row0 = blockIdx.y * 128;

  const int lane = t & 63;
  const int wav  = t >> 6;
  const int wr = (wav >> 1) * 64;
  const int wc = (wav & 1) * 64;
  const int fm = lane & 15;
  const int fq = lane >> 4;

  const int r0 = t >> 2;
  const int u0 = t & 3;

  f32x4 acc[4][4] = {};

  for (int k0 = 0; k0 < K; k0 += GBK) {
    __syncthreads();
    int4 va[2], vb[2], vc[2], vd[2];
#pragma unroll
    for (int rep = 0; rep < 2; rep++) {
      const int row = r0 + rep * 64;
      const int arow = row0 + row;
      const bool ok = arow < M;
      const size_t aoff = (size_t)arow * K + k0 + u0 * 8;
      va[rep] = ok ? *(const int4*)(Ah + aoff) : make_int4(0, 0, 0, 0);
      vb[rep] = ok ? *(const int4*)(Al + aoff) : make_int4(0, 0, 0, 0);
      const size_t boff = (size_t)(col0 + row) * K + k0 + u0 * 8;
      vc[rep] = *(const int4*)(Bh + boff);
      vd[rep] = *(const int4*)(Bl + boff);
    }
#pragma unroll
    for (int rep = 0; rep < 2; rep++) {
      const int ldso = (r0 + rep * 64) * LROW + u0 * 8;
      *(int4*)(sAh + ldso) = va[rep];
      *(int4*)(sAl + ldso) = vb[rep];
      *(int4*)(sBh + ldso) = vc[rep];
      *(int4*)(sBl + ldso) = vd[rep];
    }
    __syncthreads();

    bf16x8 fah[4], fal[4], fbh[4], fbl[4];
#pragma unroll
    for (int i = 0; i < 4; i++) {
      const int ar = (wr + i * 16 + fm) * LROW + fq * 8;
      fah[i] = *(const bf16x8*)(sAh + ar);
      fal[i] = *(const bf16x8*)(sAl + ar);
      const int br = (wc + i * 16 + fm) * LROW + fq * 8;
      fbh[i] = *(const bf16x8*)(sBh + br);
      fbl[i] = *(const bf16x8*)(sBl + br);
    }
#pragma unroll
    for (int j = 0; j < 4; j++)
#pragma unroll
      for (int i = 0; i < 4; i++) {
        acc[i][j] = __builtin_amdgcn_mfma_f32_16x16x32_bf16(fah[i], fbh[j], acc[i][j], 0, 0, 0);
        acc[i][j] = __builtin_amdgcn_mfma_f32_16x16x32_bf16(fal[i], fbh[j], acc[i][j], 0, 0, 0);
        acc[i][j] = __builtin_amdgcn_mfma_f32_16x16x32_bf16(fah[i], fbl[j], acc[i][j], 0, 0, 0);
      }
  }

#pragma unroll
  for (int i = 0; i < 4; i++) {
#pragma unroll
    for (int r = 0; r < 4; r++) {
      const int grow = row0 + wr + i * 16 + fq * 4 + r;
      if (grow < M) {
#pragma unroll
        for (int j = 0; j < 4; j++) {
          const int gcol = col0 + wc + j * 16 + fm;
          const float v = acc[i][j][r] + bias[gcol];
          C[(size_t)grow * HID + gcol] = fmaxf(v, 0.0f);
        }
      }
    }
  }
}

// ---------------- graph boundaries from sorted graph_ids ----------------
__global__ void bounds_kernel(const int* __restrict__ gid, int* __restrict__ gstart) {
  int i = blockIdx.x * blockDim.x + threadIdx.x;
  if (i >= N_NODES) return;
  const int g = gid[i];
  const int gp = (i == 0) ? -1 : gid[i - 1];
  for (int k = gp + 1; k <= g; k++) gstart[k] = i;
  if (i == N_NODES - 1) {
    for (int k = g + 1; k <= N_GRAPHS; k++) gstart[k] = N_NODES;
  }
}

// ---------------- segmented mean pool ----------------
__global__ __launch_bounds__(128) void pool_kernel(
    const float* __restrict__ h, const int* __restrict__ gstart, float* __restrict__ hg) {
  const int g = blockIdx.x;
  const int col = blockIdx.y * 128 + threadIdx.x;
  const int beg = gstart[g], end = gstart[g + 1];
  float acc = 0.f;
  int n = beg;
  for (; n + 4 <= end; n += 4) {
    float a0 = h[(size_t)(n + 0) * HID + col];
    float a1 = h[(size_t)(n + 1) * HID + col];
    float a2 = h[(size_t)(n + 2) * HID + col];
    float a3 = h[(size_t)(n + 3) * HID + col];
    acc += (a0 + a1) + (a2 + a3);
  }
  for (; n < end; n++) acc += h[(size_t)n * HID + col];
  const float inv = 1.0f / fmaxf((float)(end - beg), 1.0f);
  hg[(size_t)g * HID + col] = acc * inv;
}

// ---------------- dense layer, tiled: out[g][n0:n0+128] = relu(in[g]@W + b) ----------------
// grid (G, N/128), 256 threads: 2 k-halves x 128 cols, input row in LDS.
__global__ __launch_bounds__(256) void dense_tile(
    const float* __restrict__ in, const float* __restrict__ W,
    const float* __restrict__ b, float* __restrict__ out,
    int K, int N, int relu) {
  __shared__ float sIn[HID];
  __shared__ float red[128];
  const int g = blockIdx.x;
  const int n0 = blockIdx.y * 128;

  for (int k = threadIdx.x; k < K; k += 256) sIn[k] = in[(size_t)g * K + k];
  __syncthreads();

  const int col = threadIdx.x & 127;
  const int kh = threadIdx.x >> 7;
  const int kbeg = kh * (K >> 1);
  const int kend = kbeg + (K >> 1);
  float acc = 0.f;
#pragma unroll 8
  for (int k = kbeg; k < kend; k++)
    acc += sIn[k] * W[(size_t)k * N + n0 + col];

  if (kh == 1) red[col] = acc;
  __syncthreads();
  if (kh == 0) {
    float v = acc + red[col] + b[n0 + col];
    if (relu) v = fmaxf(v, 0.f);
    out[(size_t)g * N + n0 + col] = v;
  }
}

// ---------------- final dense: out[g][0:16], one block per graph ----------------
__global__ __launch_bounds__(256) void dense_final(
    const float* __restrict__ in, const float* __restrict__ W,
    const float* __restrict__ b, float* __restrict__ out, int K) {
  __shared__ float sIn[HID];
  __shared__ float red[256];
  const int g = blockIdx.x;
  for (int k = threadIdx.x; k < K; k += 256) sIn[k] = in[(size_t)g * K + k];
  __syncthreads();

  const int col = threadIdx.x & 15;
  const int ks = threadIdx.x >> 4;   // 0..15
  float acc = 0.f;
#pragma unroll 8
  for (int k = ks; k < K; k += 16)
    acc += sIn[k] * W[(size_t)k * N_CLASSES + col];
  red[threadIdx.x] = acc;
  __syncthreads();
#pragma unroll
  for (int off = 128; off >= 16; off >>= 1) {
    if (threadIdx.x < off) red[threadIdx.x] += red[threadIdx.x + off];
    __syncthreads();
  }
  if (threadIdx.x < 16) out[(size_t)g * N_CLASSES + threadIdx.x] = red[threadIdx.x] + b[threadIdx.x];
}

extern "C" void kernel_launch(void* const* d_in, const int* in_sizes, int n_in,
                              void* d_out, int out_size, void* d_ws, size_t ws_size,
                              hipStream_t stream) {
  const float* x   = (const float*)d_in[0];
  const int*   src = (const int*)d_in[1];
  const int*   dst = (const int*)d_in[2];
  const int*   gid = (const int*)d_in[3];
  const float* W1  = (const float*)d_in[4];  const float* b1  = (const float*)d_in[5];
  const float* W2  = (const float*)d_in[6];  const float* b2  = (const float*)d_in[7];
  const float* W3  = (const float*)d_in[8];  const float* b3  = (const float*)d_in[9];
  const float* Wc1 = (const float*)d_in[10]; const float* bc1 = (const float*)d_in[11];
  const float* Wc2 = (const float*)d_in[12]; const float* bc2 = (const float*)d_in[13];
  const float* Wc3 = (const float*)d_in[14]; const float* bc3 = (const float*)d_in[15];
  float* out = (float*)d_out;

  char* p = (char*)d_ws;
  float* bufA = (float*)p;            p += (size_t)N_NODES * HID * 4;
  u16* gh  = (u16*)p;                 p += (size_t)N_NODES * HID * 2;
  u16* gl  = (u16*)p;                 p += (size_t)N_NODES * HID * 2;
  u16* w1h = (u16*)p;                 p += (size_t)HID * IN_DIM * 2;
  u16* w1l = (u16*)p;                 p += (size_t)HID * IN_DIM * 2;
  u16* w2h = (u16*)p;                 p += (size_t)HID * HID * 2;
  u16* w2l = (u16*)p;                 p += (size_t)HID * HID * 2;
  u16* w3h = (u16*)p;                 p += (size_t)HID * HID * 2;
  u16* w3l = (u16*)p;                 p += (size_t)HID * HID * 2;
  float* dosq = (float*)p;            p += N_NODES * 4;
  float* disq = (float*)p;            p += N_NODES * 4;
  float* hg = (float*)p;              p += N_GRAPHS * HID * 4;
  float* m1 = (float*)p;              p += N_GRAPHS * HID * 4;
  float* m2 = (float*)p;              p += N_GRAPHS * HID * 4;
  int* deg_out_i = (int*)p;           p += N_NODES * 4;
  int* deg_in_i  = (int*)p;           p += N_NODES * 4;
  int* cursor    = (int*)p;           p += N_NODES * 4;
  int* row_start = (int*)p;           p += (N_NODES + 1) * 4;
  int* gstart    = (int*)p;           p += (N_GRAPHS + 1) * 4;
  int* csr_src   = (int*)p;

  // ---- CSR + degree + weight prep ----
  hipMemsetAsync(deg_out_i, 0, 3 * N_NODES * sizeof(int), stream);
  deg_kernel<<<(N_EDGES + 255) / 256, 256, 0, stream>>>(src, dst, deg_out_i, deg_in_i, N_EDGES);
  isqrt_from_int<<<(2 * N_NODES + 255) / 256, 256, 0, stream>>>(deg_out_i, dosq, 2 * N_NODES);
  scan_kernel<<<1, 1024, 0, stream>>>(deg_in_i, row_start, N_NODES);
  csr_fill<<<(N_EDGES + 255) / 256, 256, 0, stream>>>(src, dst, row_start, cursor, csr_src, N_EDGES);
  bounds_kernel<<<(N_NODES + 255) / 256, 256, 0, stream>>>(gid, gstart);
  wprep_kernel<<<(IN_DIM * HID + 255) / 256, 256, 0, stream>>>(W1, w1h, w1l, IN_DIM, HID);
  wprep_kernel<<<(HID * HID + 255) / 256, 256, 0, stream>>>(W2, w2h, w2l, HID, HID);
  wprep_kernel<<<(HID * HID + 255) / 256, 256, 0, stream>>>(W3, w3h, w3l, HID, HID);

  const dim3 ggrid(HID / 128, (N_NODES + 127) / 128);
  const int gat128 = (N_NODES + 7) / 8;
  const int gat512 = (N_NODES + 1) / 2;

  // ---- layer 1 ----
  gather_split<<<gat128, 256, 0, stream>>>(x, row_start, csr_src, dosq, disq, gh, gl, 7, 5);
  gemm_mfma<<<ggrid, 256, 0, stream>>>(gh, gl, w1h, w1l, b1, bufA, N_NODES, IN_DIM);

  // ---- layer 2 ----
  gather_split<<<gat512, 256, 0, stream>>>(bufA, row_start, csr_src, dosq, disq, gh, gl, 9, 7);
  gemm_mfma<<<ggrid, 256, 0, stream>>>(gh, gl, w2h, w2l, b2, bufA, N_NODES, HID);

  // ---- layer 3 ----
  gather_split<<<gat512, 256, 0, stream>>>(bufA, row_start, csr_src, dosq, disq, gh, gl, 9, 7);
  gemm_mfma<<<ggrid, 256, 0, stream>>>(gh, gl, w3h, w3l, b3, bufA, N_NODES, HID);

  // ---- mean pooling ----
  pool_kernel<<<dim3(N_GRAPHS, HID / 128), 128, 0, stream>>>(bufA, gstart, hg);

  // ---- classifier MLP (tiled, latency-parallel) ----
  dense_tile<<<dim3(N_GRAPHS, HID / 128), 256, 0, stream>>>(hg, Wc1, bc1, m1, HID, HID, 1);
  dense_tile<<<dim3(N_GRAPHS, HID / 128), 256, 0, stream>>>(m1, Wc2, bc2, m2, HID, HID, 1);
  dense_final<<<N_GRAPHS, 256, 0, stream>>>(m2, Wc3, bc3, out, HID);
}

// Round 6
// 428.927 us; speedup vs baseline: 10.6406x; 1.0606x over previous
//
#include <hip/hip_runtime.h>

#define N_NODES 20000
#define N_EDGES 160000
#define N_GRAPHS 64
#define IN_DIM 128
#define HID 512
#define N_CLASSES 16

typedef unsigned short u16;
typedef short bf16x8 __attribute__((ext_vector_type(8)));
typedef float f32x4 __attribute__((ext_vector_type(4)));

// round-to-nearest-even fp32 -> bf16 bits
__device__ __forceinline__ u16 bf16_rn(float x) {
  unsigned u = __float_as_uint(x);
  unsigned r = u + 0x7FFFu + ((u >> 16) & 1u);
  return (u16)(r >> 16);
}

// pack two fp32 into one int of two bf16 (lo feat in low u16)
__device__ __forceinline__ int pack2(float a0, float a1) {
  return (int)bf16_rn(a0) | ((int)bf16_rn(a1) << 16);
}

// accumulate a packed pair (h = hi-plane int, l = lo-plane int) into a[0],a[1]
__device__ __forceinline__ void addpack(float* a, int h, int l) {
  a[0] += __uint_as_float((unsigned)h << 16);
  a[0] += __uint_as_float((unsigned)l << 16);
  a[1] += __uint_as_float((unsigned)h & 0xFFFF0000u);
  a[1] += __uint_as_float((unsigned)l & 0xFFFF0000u);
}

// ---------------- degrees (int) ----------------
__global__ void deg_kernel(const int* __restrict__ src, const int* __restrict__ dst,
                           int* __restrict__ dout, int* __restrict__ din, int E) {
  int e = blockIdx.x * blockDim.x + threadIdx.x;
  if (e < E) {
    atomicAdd(dout + src[e], 1);
    atomicAdd(din + dst[e], 1);
  }
}

__global__ void isqrt_from_int(const int* __restrict__ di, float* __restrict__ f, int n) {
  int i = blockIdx.x * blockDim.x + threadIdx.x;
  if (i < n) f[i] = rsqrtf(fmaxf((float)di[i], 1.0f));
}

// ---------------- hierarchical scan: rs[i+1] = inclusive_scan(deg)[i] ----------------
__global__ __launch_bounds__(256) void scan1(const int* __restrict__ deg,
                                             int* __restrict__ rs, int* __restrict__ bsum, int n) {
  __shared__ int s[256];
  const int i = blockIdx.x * 256 + threadIdx.x;
  const int t = threadIdx.x;
  s[t] = (i < n) ? deg[i] : 0;
  __syncthreads();
#pragma unroll
  for (int off = 1; off < 256; off <<= 1) {
    int u = (t >= off) ? s[t - off] : 0;
    __syncthreads();
    s[t] += u;
    __syncthreads();
  }
  if (i < n) rs[i + 1] = s[t];
  if (t == 255) bsum[blockIdx.x] = s[255];
}

__global__ __launch_bounds__(128) void scan2(int* __restrict__ bsum, int nb) {
  __shared__ int s[128];
  const int t = threadIdx.x;
  const int v = (t < nb) ? bsum[t] : 0;
  s[t] = v;
  __syncthreads();
#pragma unroll
  for (int off = 1; off < 128; off <<= 1) {
    int u = (t >= off) ? s[t - off] : 0;
    __syncthreads();
    s[t] += u;
    __syncthreads();
  }
  if (t < nb) bsum[t] = s[t] - v;   // exclusive
}

__global__ void scan3(int* __restrict__ rs, const int* __restrict__ bsum, int n) {
  const int i = blockIdx.x * blockDim.x + threadIdx.x;
  if (i < n) rs[i + 1] += bsum[i >> 8];
  if (i == 0) rs[0] = 0;
}

// ---------------- CSR fill ----------------
__global__ void csr_fill(const int* __restrict__ src, const int* __restrict__ dst,
                         const int* __restrict__ row_start, int* __restrict__ cursor,
                         int* __restrict__ csr_src, int E) {
  int e = blockIdx.x * blockDim.x + threadIdx.x;
  if (e < E) {
    const int d = dst[e];
    const int pos = atomicAdd(cursor + d, 1);
    csr_src[row_start[d] + pos] = src[e];
  }
}

// ---------------- weight prep: W[K][N] fp32 -> Wt_hi/lo[N][K] bf16 ----------------
__global__ void wprep_kernel(const float* __restrict__ W, u16* __restrict__ th,
                             u16* __restrict__ tl, int K, int N) {
  int idx = blockIdx.x * blockDim.x + threadIdx.x;
  if (idx >= K * N) return;
  const int k = idx / N;
  const int n = idx - k * N;
  const float x = W[idx];
  const u16 hi = bf16_rn(x);
  const float hif = __uint_as_float((unsigned)hi << 16);
  const u16 lo = bf16_rn(x - hif);
  th[(size_t)n * K + k] = hi;
  tl[(size_t)n * K + k] = lo;
}

// ---------------- xprep: xs[node] = dosq[node]*x[node] as interleaved bf16 [hi128|lo128] ----------------
__global__ __launch_bounds__(256) void xprep_kernel(const float* __restrict__ x,
                                                    const float* __restrict__ dosq,
                                                    u16* __restrict__ xs) {
  const int tid = blockIdx.x * 256 + threadIdx.x;
  const int node = tid >> 4;            // 16 threads/node
  if (node >= N_NODES) return;
  const int c8 = (tid & 15) * 8;
  const float sc = dosq[node];
  const float4 v0 = *(const float4*)(x + (size_t)node * IN_DIM + c8);
  const float4 v1 = *(const float4*)(x + (size_t)node * IN_DIM + c8 + 4);
  float v[8] = {v0.x * sc, v0.y * sc, v0.z * sc, v0.w * sc,
                v1.x * sc, v1.y * sc, v1.z * sc, v1.w * sc};
  int4 hi, lo;
  int* hp = (int*)&hi; int* lp = (int*)&lo;
#pragma unroll
  for (int i = 0; i < 4; i++) {
    const u16 h0 = bf16_rn(v[2 * i]);
    const u16 h1 = bf16_rn(v[2 * i + 1]);
    const float r0 = v[2 * i]     - __uint_as_float((unsigned)h0 << 16);
    const float r1 = v[2 * i + 1] - __uint_as_float((unsigned)h1 << 16);
    hp[i] = (int)h0 | ((int)h1 << 16);
    lp[i] = (int)bf16_rn(r0) | ((int)bf16_rn(r1) << 16);
  }
  u16* o = xs + (size_t)node * 256 + c8;
  *(int4*)o = hi;
  *(int4*)(o + 128) = lo;
}

// ---------------- bf16 CSR gather: g[n] = disq[n] * sum_{s in N(n)} hin[s] ----------------
// hin rows are interleaved [hi W | lo W], already dosq-prescaled. Output same layout.
// tpn = W/8 threads per node, each thread covers 8 feats (one int4 per plane).
__global__ __launch_bounds__(256) void gather_bf16(
    const u16* __restrict__ hin, const int* __restrict__ row_start,
    const int* __restrict__ csr_src, const float* __restrict__ disq,
    u16* __restrict__ gout, int tpnshift, int W) {
  const int node = blockIdx.x * (256 >> tpnshift) + (threadIdx.x >> tpnshift);
  if (node >= N_NODES) return;
  const int c8 = (threadIdx.x & ((1 << tpnshift) - 1)) * 8;
  const int stride = 2 * W;
  const u16* base = hin + c8;

  float acc[8] = {};
  const int beg = row_start[node];
  const int end = row_start[node + 1];
  int e = beg;
  for (; e + 4 <= end; e += 4) {
    const int s0 = csr_src[e], s1 = csr_src[e + 1], s2 = csr_src[e + 2], s3 = csr_src[e + 3];
    const u16* r0 = base + (size_t)s0 * stride;
    const u16* r1 = base + (size_t)s1 * stride;
    const u16* r2 = base + (size_t)s2 * stride;
    const u16* r3 = base + (size_t)s3 * stride;
    const int4 h0 = *(const int4*)r0, l0 = *(const int4*)(r0 + W);
    const int4 h1 = *(const int4*)r1, l1 = *(const int4*)(r1 + W);
    const int4 h2 = *(const int4*)r2, l2 = *(const int4*)(r2 + W);
    const int4 h3 = *(const int4*)r3, l3 = *(const int4*)(r3 + W);
    addpack(acc + 0, h0.x, l0.x); addpack(acc + 2, h0.y, l0.y);
    addpack(acc + 4, h0.z, l0.z); addpack(acc + 6, h0.w, l0.w);
    addpack(acc + 0, h1.x, l1.x); addpack(acc + 2, h1.y, l1.y);
    addpack(acc + 4, h1.z, l1.z); addpack(acc + 6, h1.w, l1.w);
    addpack(acc + 0, h2.x, l2.x); addpack(acc + 2, h2.y, l2.y);
    addpack(acc + 4, h2.z, l2.z); addpack(acc + 6, h2.w, l2.w);
    addpack(acc + 0, h3.x, l3.x); addpack(acc + 2, h3.y, l3.y);
    addpack(acc + 4, h3.z, l3.z); addpack(acc + 6, h3.w, l3.w);
  }
  for (; e < end; e++) {
    const u16* r0 = base + (size_t)csr_src[e] * stride;
    const int4 h0 = *(const int4*)r0, l0 = *(const int4*)(r0 + W);
    addpack(acc + 0, h0.x, l0.x); addpack(acc + 2, h0.y, l0.y);
    addpack(acc + 4, h0.z, l0.z); addpack(acc + 6, h0.w, l0.w);
  }

  const float di = disq[node];
  int4 hi, lo;
  int* hp = (int*)&hi; int* lp = (int*)&lo;
#pragma unroll
  for (int i = 0; i < 4; i++) {
    const float a0 = acc[2 * i] * di;
    const float a1 = acc[2 * i + 1] * di;
    const u16 h0 = bf16_rn(a0);
    const u16 h1 = bf16_rn(a1);
    const float r0 = a0 - __uint_as_float((unsigned)h0 << 16);
    const float r1 = a1 - __uint_as_float((unsigned)h1 << 16);
    hp[i] = (int)h0 | ((int)h1 << 16);
    lp[i] = (int)bf16_rn(r0) | ((int)bf16_rn(r1) << 16);
  }
  u16* o = gout + (size_t)node * stride + c8;
  *(int4*)o = hi;
  *(int4*)(o + W) = lo;
}

// ---------------- split-bf16 MFMA GEMM ----------------
// A: interleaved bf16 planes, Ah/Al ptrs + lda (u16 elems). B: planar [N][K] hi/lo.
// mode 0: Cf[M][512] fp32 = relu(acc+bias)   (layer 3, feeds pool)
// mode 1: Cb[M][1024] u16 interleaved = bf16split(dosq[row]*relu(acc+bias))  (layers 1,2)
#define GBK 32
#define LROW 40
__global__ __launch_bounds__(256) void gemm_mfma(
    const u16* __restrict__ Ah, const u16* __restrict__ Al, int lda,
    const u16* __restrict__ Bh, const u16* __restrict__ Bl,
    const float* __restrict__ bias, const float* __restrict__ dosq,
    float* __restrict__ Cf, u16* __restrict__ Cb,
    int M, int K, int mode) {
  __shared__ u16 sAh[128 * LROW];
  __shared__ u16 sAl[128 * LROW];
  __shared__ u16 sBh[128 * LROW];
  __shared__ u16 sBl[128 * LROW];

  const int t = threadIdx.x;
  const int col0 = blockIdx.x * 128;
  const int row0 = blockIdx.y * 128;

  const int lane = t & 63;
  const int wav  = t >> 6;
  const int wr = (wav >> 1) * 64;
  const int wc = (wav & 1) * 64;
  const int fm = lane & 15;
  const int fq = lane >> 4;

  const int r0 = t >> 2;
  const int u0 = t & 3;

  f32x4 acc[4][4] = {};

  for (int k0 = 0; k0 < K; k0 += GBK) {
    __syncthreads();
    int4 va[2], vb[2], vc[2], vd[2];
#pragma unroll
    for (int rep = 0; rep < 2; rep++) {
      const int row = r0 + rep * 64;
      const int arow = row0 + row;
      const bool ok = arow < M;
      const size_t aoff = (size_t)arow * lda + k0 + u0 * 8;
      va[rep] = ok ? *(const int4*)(Ah + aoff) : make_int4(0, 0, 0, 0);
      vb[rep] = ok ? *(const int4*)(Al + aoff) : make_int4(0, 0, 0, 0);
      const size_t boff = (size_t)(col0 + row) * K + k0 + u0 * 8;
      vc[rep] = *(const int4*)(Bh + boff);
      vd[rep] = *(const int4*)(Bl + boff);
    }
#pragma unroll
    for (int rep = 0; rep < 2; rep++) {
      const int ldso = (r0 + rep * 64) * LROW + u0 * 8;
      *(int4*)(sAh + ldso) = va[rep];
      *(int4*)(sAl + ldso) = vb[rep];
      *(int4*)(sBh + ldso) = vc[rep];
      *(int4*)(sBl + ldso) = vd[rep];
    }
    __syncthreads();

    bf16x8 fah[4], fal[4], fbh[4], fbl[4];
#pragma unroll
    for (int i = 0; i < 4; i++) {
      const int ar = (wr + i * 16 + fm) * LROW + fq * 8;
      fah[i] = *(const bf16x8*)(sAh + ar);
      fal[i] = *(const bf16x8*)(sAl + ar);
      const int br = (wc + i * 16 + fm) * LROW + fq * 8;
      fbh[i] = *(const bf16x8*)(sBh + br);
      fbl[i] = *(const bf16x8*)(sBl + br);
    }
#pragma unroll
    for (int j = 0; j < 4; j++)
#pragma unroll
      for (int i = 0; i < 4; i++) {
        acc[i][j] = __builtin_amdgcn_mfma_f32_16x16x32_bf16(fah[i], fbh[j], acc[i][j], 0, 0, 0);
        acc[i][j] = __builtin_amdgcn_mfma_f32_16x16x32_bf16(fal[i], fbh[j], acc[i][j], 0, 0, 0);
        acc[i][j] = __builtin_amdgcn_mfma_f32_16x16x32_bf16(fah[i], fbl[j], acc[i][j], 0, 0, 0);
      }
  }

#pragma unroll
  for (int i = 0; i < 4; i++) {
#pragma unroll
    for (int r = 0; r < 4; r++) {
      const int grow = row0 + wr + i * 16 + fq * 4 + r;
      if (grow < M) {
        if (mode == 0) {
#pragma unroll
          for (int j = 0; j < 4; j++) {
            const int gcol = col0 + wc + j * 16 + fm;
            Cf[(size_t)grow * HID + gcol] = fmaxf(acc[i][j][r] + bias[gcol], 0.0f);
          }
        } else {
          const float dsc = dosq[grow];
#pragma unroll
          for (int j = 0; j < 4; j++) {
            const int gcol = col0 + wc + j * 16 + fm;
            const float v = fmaxf(acc[i][j][r] + bias[gcol], 0.0f) * dsc;
            const u16 hb = bf16_rn(v);
            const float hf = __uint_as_float((unsigned)hb << 16);
            Cb[(size_t)grow * 1024 + gcol] = hb;
            Cb[(size_t)grow * 1024 + 512 + gcol] = bf16_rn(v - hf);
          }
        }
      }
    }
  }
}

// ---------------- graph boundaries from sorted graph_ids ----------------
__global__ void bounds_kernel(const int* __restrict__ gid, int* __restrict__ gstart) {
  int i = blockIdx.x * blockDim.x + threadIdx.x;
  if (i >= N_NODES) return;
  const int g = gid[i];
  const int gp = (i == 0) ? -1 : gid[i - 1];
  for (int k = gp + 1; k <= g; k++) gstart[k] = i;
  if (i == N_NODES - 1) {
    for (int k = g + 1; k <= N_GRAPHS; k++) gstart[k] = N_NODES;
  }
}

// ---------------- segmented mean pool ----------------
__global__ __launch_bounds__(128) void pool_kernel(
    const float* __restrict__ h, const int* __restrict__ gstart, float* __restrict__ hg) {
  const int g = blockIdx.x;
  const int col = blockIdx.y * 128 + threadIdx.x;
  const int beg = gstart[g], end = gstart[g + 1];
  float acc = 0.f;
  int n = beg;
  for (; n + 4 <= end; n += 4) {
    float a0 = h[(size_t)(n + 0) * HID + col];
    float a1 = h[(size_t)(n + 1) * HID + col];
    float a2 = h[(size_t)(n + 2) * HID + col];
    float a3 = h[(size_t)(n + 3) * HID + col];
    acc += (a0 + a1) + (a2 + a3);
  }
  for (; n < end; n++) acc += h[(size_t)n * HID + col];
  const float inv = 1.0f / fmaxf((float)(end - beg), 1.0f);
  hg[(size_t)g * HID + col] = acc * inv;
}

// ---------------- dense layer, tiled ----------------
__global__ __launch_bounds__(256) void dense_tile(
    const float* __restrict__ in, const float* __restrict__ W,
    const float* __restrict__ b, float* __restrict__ out,
    int K, int N, int relu) {
  __shared__ float sIn[HID];
  __shared__ float red[128];
  const int g = blockIdx.x;
  const int n0 = blockIdx.y * 128;

  for (int k = threadIdx.x; k < K; k += 256) sIn[k] = in[(size_t)g * K + k];
  __syncthreads();

  const int col = threadIdx.x & 127;
  const int kh = threadIdx.x >> 7;
  const int kbeg = kh * (K >> 1);
  const int kend = kbeg + (K >> 1);
  float acc = 0.f;
#pragma unroll 8
  for (int k = kbeg; k < kend; k++)
    acc += sIn[k] * W[(size_t)k * N + n0 + col];

  if (kh == 1) red[col] = acc;
  __syncthreads();
  if (kh == 0) {
    float v = acc + red[col] + b[n0 + col];
    if (relu) v = fmaxf(v, 0.f);
    out[(size_t)g * N + n0 + col] = v;
  }
}

// ---------------- final dense ----------------
__global__ __launch_bounds__(256) void dense_final(
    const float* __restrict__ in, const float* __restrict__ W,
    const float* __restrict__ b, float* __restrict__ out, int K) {
  __shared__ float sIn[HID];
  __shared__ float red[256];
  const int g = blockIdx.x;
  for (int k = threadIdx.x; k < K; k += 256) sIn[k] = in[(size_t)g * K + k];
  __syncthreads();

  const int col = threadIdx.x & 15;
  const int ks = threadIdx.x >> 4;
  float acc = 0.f;
#pragma unroll 8
  for (int k = ks; k < K; k += 16)
    acc += sIn[k] * W[(size_t)k * N_CLASSES + col];
  red[threadIdx.x] = acc;
  __syncthreads();
#pragma unroll
  for (int off = 128; off >= 16; off >>= 1) {
    if (threadIdx.x < off) red[threadIdx.x] += red[threadIdx.x + off];
    __syncthreads();
  }
  if (threadIdx.x < 16) out[(size_t)g * N_CLASSES + threadIdx.x] = red[threadIdx.x] + b[threadIdx.x];
}

extern "C" void kernel_launch(void* const* d_in, const int* in_sizes, int n_in,
                              void* d_out, int out_size, void* d_ws, size_t ws_size,
                              hipStream_t stream) {
  const float* x   = (const float*)d_in[0];
  const int*   src = (const int*)d_in[1];
  const int*   dst = (const int*)d_in[2];
  const int*   gid = (const int*)d_in[3];
  const float* W1  = (const float*)d_in[4];  const float* b1  = (const float*)d_in[5];
  const float* W2  = (const float*)d_in[6];  const float* b2  = (const float*)d_in[7];
  const float* W3  = (const float*)d_in[8];  const float* b3  = (const float*)d_in[9];
  const float* Wc1 = (const float*)d_in[10]; const float* bc1 = (const float*)d_in[11];
  const float* Wc2 = (const float*)d_in[12]; const float* bc2 = (const float*)d_in[13];
  const float* Wc3 = (const float*)d_in[14]; const float* bc3 = (const float*)d_in[15];
  float* out = (float*)d_out;

  char* p = (char*)d_ws;
  u16* slotA = (u16*)p;               p += (size_t)N_NODES * 1024 * 2;  // h bf16 interleaved / fp32 pool input
  u16* slotB = (u16*)p;               p += (size_t)N_NODES * 1024 * 2;  // g bf16 interleaved
  u16* w1h = (u16*)p;                 p += (size_t)HID * IN_DIM * 2;
  u16* w1l = (u16*)p;                 p += (size_t)HID * IN_DIM * 2;
  u16* w2h = (u16*)p;                 p += (size_t)HID * HID * 2;
  u16* w2l = (u16*)p;                 p += (size_t)HID * HID * 2;
  u16* w3h = (u16*)p;                 p += (size_t)HID * HID * 2;
  u16* w3l = (u16*)p;                 p += (size_t)HID * HID * 2;
  float* dosq = (float*)p;            p += N_NODES * 4;
  float* disq = (float*)p;            p += N_NODES * 4;
  float* hg = (float*)p;              p += N_GRAPHS * HID * 4;
  float* m1 = (float*)p;              p += N_GRAPHS * HID * 4;
  float* m2 = (float*)p;              p += N_GRAPHS * HID * 4;
  int* deg_out_i = (int*)p;           p += N_NODES * 4;
  int* deg_in_i  = (int*)p;           p += N_NODES * 4;
  int* cursor    = (int*)p;           p += N_NODES * 4;
  int* row_start = (int*)p;           p += (N_NODES + 1) * 4;
  int* bsum      = (int*)p;           p += 128 * 4;
  int* gstart    = (int*)p;           p += (N_GRAPHS + 1) * 4;
  int* csr_src   = (int*)p;

  float* bufA = (float*)slotA;   // aliases slotA for layer-3 fp32 output (same 40.96 MB)

  // ---- CSR + degree + weight prep ----
  hipMemsetAsync(deg_out_i, 0, 3 * N_NODES * sizeof(int), stream);
  deg_kernel<<<(N_EDGES + 255) / 256, 256, 0, stream>>>(src, dst, deg_out_i, deg_in_i, N_EDGES);
  isqrt_from_int<<<(2 * N_NODES + 255) / 256, 256, 0, stream>>>(deg_out_i, dosq, 2 * N_NODES);
  const int nsb = (N_NODES + 255) / 256;
  scan1<<<nsb, 256, 0, stream>>>(deg_in_i, row_start, bsum, N_NODES);
  scan2<<<1, 128, 0, stream>>>(bsum, nsb);
  scan3<<<nsb, 256, 0, stream>>>(row_start, bsum, N_NODES);
  csr_fill<<<(N_EDGES + 255) / 256, 256, 0, stream>>>(src, dst, row_start, cursor, csr_src, N_EDGES);
  bounds_kernel<<<(N_NODES + 255) / 256, 256, 0, stream>>>(gid, gstart);
  wprep_kernel<<<(IN_DIM * HID + 255) / 256, 256, 0, stream>>>(W1, w1h, w1l, IN_DIM, HID);
  wprep_kernel<<<(HID * HID + 255) / 256, 256, 0, stream>>>(W2, w2h, w2l, HID, HID);
  wprep_kernel<<<(HID * HID + 255) / 256, 256, 0, stream>>>(W3, w3h, w3l, HID, HID);

  const dim3 ggrid(HID / 128, (N_NODES + 127) / 128);
  const int gat128_blocks = (N_NODES * 16 + 255) / 256;   // tpn=16
  const int gat512_blocks = (N_NODES * 64 + 255) / 256;   // tpn=64

  // ---- layer 1: xprep -> gather(bf16,W=128) -> GEMM K=128 (out: bf16 interleaved, prescaled) ----
  xprep_kernel<<<(N_NODES * 16 + 255) / 256, 256, 0, stream>>>(x, dosq, slotB /*reuse as xs*/);
  // gather from slotB(xs) would alias its own output; use slotA as xs instead:
  // (slotA is free before layer 1) -- redo: xprep wrote to slotB; gather must write g1 elsewhere.
  // g1 lives in slotA[0 .. 20000*256), then gemm writes h1 to slotB? h1 needs 20000*1024.
  // Simplest: xs in slotB, g1 in slotA (stride 256), gemm1 reads slotA writes slotB (h1),
  // gather2 reads slotB writes slotA (g2), gemm2 reads slotA writes slotB (h2),
  // gather3 reads slotB writes slotA (g3), gemm3 reads slotA(g3) writes bufA... bufA==slotA CONFLICT.
  // Fix: gemm3 writes fp32 to slotB (reinterpret), pool reads slotB.
  gather_bf16<<<gat128_blocks, 256, 0, stream>>>(slotB, row_start, csr_src, disq,
                                                 (u16*)slotA, 4, 128);
  gemm_mfma<<<ggrid, 256, 0, stream>>>((u16*)slotA, (u16*)slotA + 128, 256,
                                       w1h, w1l, b1, dosq, nullptr, slotB,
                                       N_NODES, IN_DIM, 1);

  // ---- layer 2 ----
  gather_bf16<<<gat512_blocks, 256, 0, stream>>>(slotB, row_start, csr_src, disq,
                                                 (u16*)slotA, 6, 512);
  gemm_mfma<<<ggrid, 256, 0, stream>>>((u16*)slotA, (u16*)slotA + 512, 1024,
                                       w2h, w2l, b2, dosq, nullptr, slotB,
                                       N_NODES, HID, 1);

  // ---- layer 3 (fp32 out for pooling) ----
  gather_bf16<<<gat512_blocks, 256, 0, stream>>>(slotB, row_start, csr_src, disq,
                                                 (u16*)slotA, 6, 512);
  float* h3 = (float*)slotB;
  gemm_mfma<<<ggrid, 256, 0, stream>>>((u16*)slotA, (u16*)slotA + 512, 1024,
                                       w3h, w3l, b3, dosq, h3, nullptr,
                                       N_NODES, HID, 0);

  // ---- mean pooling ----
  pool_kernel<<<dim3(N_GRAPHS, HID / 128), 128, 0, stream>>>(h3, gstart, hg);

  // ---- classifier MLP ----
  dense_tile<<<dim3(N_GRAPHS, HID / 128), 256, 0, stream>>>(hg, Wc1, bc1, m1, HID, HID, 1);
  dense_tile<<<dim3(N_GRAPHS, HID / 128), 256, 0, stream>>>(m1, Wc2, bc2, m2, HID, HID, 1);
  dense_final<<<N_GRAPHS, 256, 0, stream>>>(m2, Wc3, bc3, out, HID);
}